// Round 7
// baseline (563.293 us; speedup 1.0000x reference)
//
#include <hip/hip_runtime.h>
#include <hip/hip_fp16.h>

#define NN 50000
#define NM 50000
#define F  128
#define NBUK 782      // ceil(50000/64) buckets of 64 dest ids
#define CHSZ 8192     // edges per sort chunk
#define GROWS 12      // gemm rows per block
#define DEGB 256      // degree bins for segment sort
typedef unsigned short ushort_t;

union HF4 { float4 f4; __half2 h2[4]; };

// ---------------- block-scan helpers ---------------------------------------------
__device__ __forceinline__ int wscan64(int v, int lane) {
    int x = v;
#pragma unroll
    for (int s = 1; s < 64; s <<= 1) {
        int u = __shfl_up(x, s, 64);
        if (lane >= s) x += u;
    }
    return x;   // inclusive
}

__device__ __forceinline__ int bscan256(int v, int* s5, int* tot) {
    int t = threadIdx.x, lane = t & 63, wid = t >> 6;
    int incl = wscan64(v, lane);
    if (lane == 63) s5[wid] = incl;
    __syncthreads();
    if (t == 0) {
        int a = 0;
#pragma unroll
        for (int j = 0; j < 4; ++j) { int x = s5[j]; s5[j] = a; a += x; }
        s5[4] = a;
    }
    __syncthreads();
    int ex = incl - v + s5[wid];
    *tot = s5[4];
    __syncthreads();
    return ex;
}

// ---------------- fat kernel: chunksort blocks [0,nsort) + gemm blocks -----------
struct GemmSmem { __half sWh[128 * 128]; float sX[GROWS * 128]; };   // 32KB + 6KB
struct SortSmem { int hist[NBUK]; int cursor[NBUK]; int pairs[CHSZ]; int s5[5]; }; // 39KB
union alignas(16) FatSmem { GemmSmem g; SortSmem s; };

__global__ __launch_bounds__(256) void fat_k(const float* __restrict__ X,
                                             const float* __restrict__ W,
                                             __half2* __restrict__ xs,     // sliced x table
                                             const int* __restrict__ nodes,
                                             const int* __restrict__ hedges,
                                             int* __restrict__ gchunk0, int* __restrict__ gchunk1,
                                             int* __restrict__ ghist, int* __restrict__ gstart,
                                             int E, int NCH, int nsort) {
    __shared__ FatSmem u;
    int t = threadIdx.x;

    if ((int)blockIdx.x < nsort) {
        // ---------------- chunksort ----------------
        int dir = blockIdx.x / NCH;
        int c   = blockIdx.x % NCH;
        const int* key = dir ? nodes  : hedges;
        const int* pay = dir ? hedges : nodes;
        int* gchunk    = dir ? gchunk1 : gchunk0;
        int e0 = c * CHSZ, e1 = min(E, e0 + CHSZ);

        for (int i = t; i < NBUK; i += 256) u.s.hist[i] = 0;
        __syncthreads();
        for (int e = e0 + t; e < e1; e += 256) atomicAdd(&u.s.hist[key[e] >> 6], 1);
        __syncthreads();

        int carry = 0;
        for (int base = 0; base < NBUK; base += 256) {
            int i = base + t;
            int v = (i < NBUK) ? u.s.hist[i] : 0;
            int tot;
            int ex = bscan256(v, u.s.s5, &tot);
            if (i < NBUK) u.s.cursor[i] = ex + carry;
            carry += tot;
        }
        __syncthreads();

        for (int b = t; b < NBUK; b += 256) {
            size_t idx = ((size_t)dir * NBUK + b) * NCH + c;
            ghist[idx]  = u.s.hist[b];
            gstart[idx] = u.s.cursor[b];
        }
        __syncthreads();

        for (int e = e0 + t; e < e1; e += 256) {
            int k = key[e];
            int pos = atomicAdd(&u.s.cursor[k >> 6], 1);
            u.s.pairs[pos] = ((k & 63) << 16) | pay[e];
        }
        __syncthreads();

        int n = e1 - e0;
        for (int i = t; i < n; i += 256) gchunk[(size_t)c * CHSZ + i] = u.s.pairs[i];
    } else {
        // ---------------- gemm: x = X @ W -> fp16 sliced table ----------------
        int gb = blockIdx.x - nsort;

        __half2* sWh2 = (__half2*)u.g.sWh;
        for (int i = t; i < 4096; i += 256) {
            float4 wv = ((const float4*)W)[i];
            int k = i >> 5, cc = i & 31;
            sWh2[k * 64 + 2 * cc]     = __floats2half2_rn(wv.x, wv.y);
            sWh2[k * 64 + 2 * cc + 1] = __floats2half2_rn(wv.z, wv.w);
        }
        const float4* X4 = (const float4*)X;
        size_t gbase = (size_t)gb * GROWS * 32;
        for (int i = t; i < GROWS * 32; i += 256) {
            size_t gi = gbase + i;
            ((float4*)u.g.sX)[i] = (gi < (size_t)NN * 32) ? X4[gi] : make_float4(0.f, 0.f, 0.f, 0.f);
        }
        __syncthreads();

        int l = t & 63, w = t >> 6;           // lane owns col pair (2l,2l+1); wave owns 3 rows
        float acc[3][2] = {};
        for (int k0 = 0; k0 < 128; k0 += 4) {
            float4 xr0 = *(const float4*)&u.g.sX[(w * 3 + 0) * 128 + k0];
            float4 xr1 = *(const float4*)&u.g.sX[(w * 3 + 1) * 128 + k0];
            float4 xr2 = *(const float4*)&u.g.sX[(w * 3 + 2) * 128 + k0];
            const float* x0 = (const float*)&xr0;
            const float* x1 = (const float*)&xr1;
            const float* x2p = (const float*)&xr2;
#pragma unroll
            for (int j = 0; j < 4; ++j) {
                float2 wv = __half22float2(sWh2[(k0 + j) * 64 + l]);
                acc[0][0] = fmaf(x0[j], wv.x, acc[0][0]); acc[0][1] = fmaf(x0[j], wv.y, acc[0][1]);
                acc[1][0] = fmaf(x1[j], wv.x, acc[1][0]); acc[1][1] = fmaf(x1[j], wv.y, acc[1][1]);
                acc[2][0] = fmaf(x2p[j], wv.x, acc[2][0]); acc[2][1] = fmaf(x2p[j], wv.y, acc[2][1]);
            }
        }
        int s = l >> 3, cc = l & 7;           // slice, half2-col within slice
#pragma unroll
        for (int r = 0; r < 3; ++r) {
            int row = gb * GROWS + w * 3 + r;
            if (row < NN)
                xs[((size_t)s * NN + row) * 8 + cc] = __floats2half2_rn(acc[r][0], acc[r][1]);
        }
    }
}

// ---------------- 2: bucket totals -> global bucket starts -----------------------
__global__ __launch_bounds__(1024) void bucketbase_k(const int* __restrict__ ghist,
                                                     int* __restrict__ bstart,
                                                     int* __restrict__ off0, int* __restrict__ off1,
                                                     int E, int NCH) {
    __shared__ int s16[17];
    int dir = blockIdx.x;
    int t = threadIdx.x, lane = t & 63, wid = t >> 6;
    int v = 0;
    if (t < NBUK) {
        const int* row = ghist + ((size_t)dir * NBUK + t) * NCH;
        int s = 0;
#pragma unroll 4
        for (int c = 0; c < NCH; ++c) s += row[c];
        v = s;
    }
    int incl = wscan64(v, lane);
    if (lane == 63) s16[wid] = incl;
    __syncthreads();
    if (t < 16) {
        int x = s16[t], y = x;
#pragma unroll
        for (int s = 1; s < 16; s <<= 1) {
            int u = __shfl_up(y, s, 64);
            if (t >= s) y += u;
        }
        s16[t] = y - x;
    }
    __syncthreads();
    int ex = incl - v + s16[wid];
    if (t < NBUK) bstart[dir * NBUK + t] = ex;
    if (t == 0) (dir ? off1 : off0)[50000] = E;
}

// ---------------- 3: per-bucket merge + fine sort + scatter ----------------------
__global__ __launch_bounds__(256) void merge_scatter_k(const int* __restrict__ gchunk0, const int* __restrict__ gchunk1,
                                                       const int* __restrict__ ghist, const int* __restrict__ gstart,
                                                       const int* __restrict__ bstart,
                                                       ushort_t* __restrict__ adj0, ushort_t* __restrict__ adj1,
                                                       int* __restrict__ off0, int* __restrict__ off1,
                                                       int NCH) {
    __shared__ int ssrc[256];
    __shared__ int sdst[257];
    __shared__ int s5[5];
    __shared__ int pairsS[CHSZ];
    __shared__ int fcnt[64], foff[64], fcur[64];

    int dir = blockIdx.x / NBUK;
    int b   = blockIdx.x % NBUK;
    int t   = threadIdx.x;
    const int* gchunk   = dir ? gchunk1 : gchunk0;
    ushort_t* adj       = dir ? adj1 : adj0;
    int* offD           = dir ? off1 : off0;

    int len = 0, src = 0;
    if (t < NCH) {
        size_t idx = ((size_t)dir * NBUK + b) * NCH + t;
        len = ghist[idx];
        src = gstart[idx];
    }
    ssrc[t] = src;
    int tot;
    int ex = bscan256(len, s5, &tot);
    sdst[t] = ex;
    if (t == 0) sdst[256] = 0x7FFFFFFF;
    if (t < 64) fcnt[t] = 0;
    __syncthreads();
    int T = tot;

    int per = (T + 255) >> 8;
    int i0 = t * per, i1 = min(T, i0 + per);
    if (i0 < i1) {
        int lo = 0, hi = 255;
        while (lo < hi) {
            int mid = (lo + hi + 1) >> 1;
            if (sdst[mid] <= i0) lo = mid; else hi = mid - 1;
        }
        int c = lo;
        for (int i = i0; i < i1; ++i) {
            while (c < 255 && sdst[c + 1] <= i) ++c;
            int p = gchunk[(size_t)c * CHSZ + ssrc[c] + (i - sdst[c])];
            pairsS[i] = p;
            atomicAdd(&fcnt[p >> 16], 1);
        }
    }
    __syncthreads();

    int bst = bstart[dir * NBUK + b];
    if (t < 64) {
        int x = fcnt[t];
        int y = wscan64(x, t);
        foff[t] = y - x;
        fcur[t] = y - x;
        int d = b * 64 + t;
        if (d < 50000) offD[d] = bst + foff[t];
    }
    __syncthreads();

    for (int i = t; i < T; i += 256) {
        int p = pairsS[i];
        int slot = atomicAdd(&fcur[p >> 16], 1);
        adj[(size_t)bst + slot] = (ushort_t)(p & 0xFFFF);
    }
}

// ---------------- degree-sort: hist -> scan -> fill perm -------------------------
__global__ void deghist_k(const int* __restrict__ off0, const int* __restrict__ off1,
                          int* __restrict__ dbin) {
    int i = blockIdx.x * 256 + threadIdx.x;
    if (i < 2 * NN) {
        int dir = (i < NN) ? 0 : 1;
        const int* off = dir ? off1 : off0;
        int s = dir ? i - NN : i;
        int d = min(off[s + 1] - off[s], DEGB - 1);
        atomicAdd(&dbin[dir * DEGB + d], 1);
    }
}

__global__ __launch_bounds__(256) void degscan_k(const int* __restrict__ dbin,
                                                 int* __restrict__ dcur) {
    __shared__ int s5[5];
    for (int dir = 0; dir < 2; ++dir) {
        int v = dbin[dir * DEGB + threadIdx.x];
        int tot;
        int ex = bscan256(v, s5, &tot);
        dcur[dir * DEGB + threadIdx.x] = ex;
    }
}

__global__ void degfill_k(const int* __restrict__ off0, const int* __restrict__ off1,
                          int* __restrict__ dcur,
                          int* __restrict__ perm0, int* __restrict__ perm1) {
    int i = blockIdx.x * 256 + threadIdx.x;
    if (i < 2 * NN) {
        int dir = (i < NN) ? 0 : 1;
        const int* off = dir ? off1 : off0;
        int s = dir ? i - NN : i;
        int d = min(off[s + 1] - off[s], DEGB - 1);
        int pos = atomicAdd(&dcur[dir * DEGB + d], 1);
        (dir ? perm1 : perm0)[pos] = s;
    }
}

// ---------------- pass A (sliced, sorted, G=2): m_s[h] = B_inv * sum x_s[v] ------
__global__ __launch_bounds__(256) void agg_a_k(const __half2* __restrict__ xs,
                                               const ushort_t* __restrict__ adj,
                                               const int* __restrict__ off,
                                               const int* __restrict__ perm,
                                               __half2* __restrict__ ms) {
    int t = threadIdx.x;
    int s = blockIdx.x & 7;
    int gi = (blockIdx.x >> 3) * 128 + (t >> 1);
    int c2 = t & 1;
    if (gi >= NM) return;
    int seg = perm[gi];
    int p0 = off[seg], p1 = off[seg + 1];
    const __half2* base = xs + (size_t)s * NN * 8 + c2 * 4;
    float a0 = 0.f, a1 = 0.f, a2 = 0.f, a3 = 0.f, a4 = 0.f, a5 = 0.f, a6 = 0.f, a7 = 0.f;
    int i = p0;
    for (; i + 4 <= p1; i += 4) {
        int n0 = adj[i], n1 = adj[i + 1], n2 = adj[i + 2], n3 = adj[i + 3];
        HF4 u0, u1, u2, u3;
        u0.f4 = *(const float4*)(base + (size_t)n0 * 8);
        u1.f4 = *(const float4*)(base + (size_t)n1 * 8);
        u2.f4 = *(const float4*)(base + (size_t)n2 * 8);
        u3.f4 = *(const float4*)(base + (size_t)n3 * 8);
#pragma unroll
        for (int k = 0; k < 4; ++k) {
            float2 f0 = __half22float2(u0.h2[k]);
            float2 f1 = __half22float2(u1.h2[k]);
            float2 f2 = __half22float2(u2.h2[k]);
            float2 f3 = __half22float2(u3.h2[k]);
            float sx = (f0.x + f1.x) + (f2.x + f3.x);
            float sy = (f0.y + f1.y) + (f2.y + f3.y);
            if (k == 0) { a0 += sx; a1 += sy; }
            else if (k == 1) { a2 += sx; a3 += sy; }
            else if (k == 2) { a4 += sx; a5 += sy; }
            else { a6 += sx; a7 += sy; }
        }
    }
    for (; i < p1; ++i) {
        HF4 u0;
        u0.f4 = *(const float4*)(base + (size_t)adj[i] * 8);
        float2 f;
        f = __half22float2(u0.h2[0]); a0 += f.x; a1 += f.y;
        f = __half22float2(u0.h2[1]); a2 += f.x; a3 += f.y;
        f = __half22float2(u0.h2[2]); a4 += f.x; a5 += f.y;
        f = __half22float2(u0.h2[3]); a6 += f.x; a7 += f.y;
    }
    float inv = (p1 > p0) ? 1.0f / (float)(p1 - p0) : 0.0f;
    HF4 w;
    w.h2[0] = __floats2half2_rn(a0 * inv, a1 * inv);
    w.h2[1] = __floats2half2_rn(a2 * inv, a3 * inv);
    w.h2[2] = __floats2half2_rn(a4 * inv, a5 * inv);
    w.h2[3] = __floats2half2_rn(a6 * inv, a7 * inv);
    *(float4*)(ms + ((size_t)s * NM + seg) * 8 + c2 * 4) = w.f4;
}

// ---------------- pass B (sliced, sorted, G=2): logits -> fp16 -------------------
__global__ __launch_bounds__(256) void agg_b_k(const __half2* __restrict__ ms,
                                               const ushort_t* __restrict__ adj,
                                               const int* __restrict__ off,
                                               const int* __restrict__ perm,
                                               const float* __restrict__ bias,
                                               __half2* __restrict__ lgh) {
    int t = threadIdx.x;
    int s = blockIdx.x & 7;
    int gi = (blockIdx.x >> 3) * 128 + (t >> 1);
    int c2 = t & 1;
    if (gi >= NN) return;
    int seg = perm[gi];
    int p0 = off[seg], p1 = off[seg + 1];
    const __half2* base = ms + (size_t)s * NM * 8 + c2 * 4;
    float a0 = 0.f, a1 = 0.f, a2 = 0.f, a3 = 0.f, a4 = 0.f, a5 = 0.f, a6 = 0.f, a7 = 0.f;
    int i = p0;
    for (; i + 4 <= p1; i += 4) {
        int n0 = adj[i], n1 = adj[i + 1], n2 = adj[i + 2], n3 = adj[i + 3];
        HF4 u0, u1, u2, u3;
        u0.f4 = *(const float4*)(base + (size_t)n0 * 8);
        u1.f4 = *(const float4*)(base + (size_t)n1 * 8);
        u2.f4 = *(const float4*)(base + (size_t)n2 * 8);
        u3.f4 = *(const float4*)(base + (size_t)n3 * 8);
#pragma unroll
        for (int k = 0; k < 4; ++k) {
            float2 f0 = __half22float2(u0.h2[k]);
            float2 f1 = __half22float2(u1.h2[k]);
            float2 f2 = __half22float2(u2.h2[k]);
            float2 f3 = __half22float2(u3.h2[k]);
            float sx = (f0.x + f1.x) + (f2.x + f3.x);
            float sy = (f0.y + f1.y) + (f2.y + f3.y);
            if (k == 0) { a0 += sx; a1 += sy; }
            else if (k == 1) { a2 += sx; a3 += sy; }
            else if (k == 2) { a4 += sx; a5 += sy; }
            else { a6 += sx; a7 += sy; }
        }
    }
    for (; i < p1; ++i) {
        HF4 u0;
        u0.f4 = *(const float4*)(base + (size_t)adj[i] * 8);
        float2 f;
        f = __half22float2(u0.h2[0]); a0 += f.x; a1 += f.y;
        f = __half22float2(u0.h2[1]); a2 += f.x; a3 += f.y;
        f = __half22float2(u0.h2[2]); a4 += f.x; a5 += f.y;
        f = __half22float2(u0.h2[3]); a6 += f.x; a7 += f.y;
    }
    float inv = (p1 > p0) ? 1.0f / (float)(p1 - p0) : 0.0f;
    const float2* bias2 = (const float2*)bias;
    float2 b0 = bias2[s * 8 + c2 * 4];
    float2 b1 = bias2[s * 8 + c2 * 4 + 1];
    float2 b2 = bias2[s * 8 + c2 * 4 + 2];
    float2 b3 = bias2[s * 8 + c2 * 4 + 3];
    HF4 w;
    w.h2[0] = __floats2half2_rn(a0 * inv + b0.x, a1 * inv + b0.y);
    w.h2[1] = __floats2half2_rn(a2 * inv + b1.x, a3 * inv + b1.y);
    w.h2[2] = __floats2half2_rn(a4 * inv + b2.x, a5 * inv + b2.y);
    w.h2[3] = __floats2half2_rn(a6 * inv + b3.x, a7 * inv + b3.y);
    *(float4*)(lgh + ((size_t)s * NN + seg) * 8 + c2 * 4) = w.f4;
}

// ---------------- final: row softmax from sliced fp16 logits -> d_out ------------
__global__ __launch_bounds__(256) void softmax_k(const __half2* __restrict__ lgh,
                                                 float2* __restrict__ out) {
    int v = blockIdx.x * 4 + (threadIdx.x >> 6);
    int l = threadIdx.x & 63;
    float2 val = __half22float2(lgh[((size_t)(l >> 3) * NN + v) * 8 + (l & 7)]);
    float mx = fmaxf(val.x, val.y);
#pragma unroll
    for (int s2 = 32; s2 >= 1; s2 >>= 1) mx = fmaxf(mx, __shfl_xor(mx, s2, 64));
    float e0 = __expf(val.x - mx), e1 = __expf(val.y - mx);
    float sm = e0 + e1;
#pragma unroll
    for (int s2 = 32; s2 >= 1; s2 >>= 1) sm += __shfl_xor(sm, s2, 64);
    float r = 1.0f / sm;
    out[(size_t)v * 64 + l] = make_float2(e0 * r, e1 * r);
}

// ---------------- launcher -------------------------------------------------------
extern "C" void kernel_launch(void* const* d_in, const int* in_sizes, int n_in,
                              void* d_out, int out_size, void* d_ws, size_t ws_size,
                              hipStream_t stream) {
    const float* X  = (const float*)d_in[0];
    const int*   ei = (const int*)d_in[1];
    const float* W  = (const float*)d_in[2];
    const float* b  = (const float*)d_in[3];

    int E = in_sizes[1] / 2;
    const int* nodes  = ei;
    const int* hedges = ei + E;
    int NCH = (E + CHSZ - 1) / CHSZ;       // 196 for E=1.6M (must be <= 256)
    int nsort = 2 * NCH;
    int gemmb = (NN + GROWS - 1) / GROWS;

    // workspace layout (~62 MB)
    char* p = (char*)d_ws;
    __half2* xs = (__half2*)p;            p += (size_t)NN * F * 2;            // sliced x, 12.8MB
    __half2* ms = (__half2*)p;            p += (size_t)NM * F * 2;            // sliced m, 12.8MB
    ushort_t* adj0 = (ushort_t*)p;        p += (size_t)E * 2;                 // 3.2MB
    ushort_t* adj1 = (ushort_t*)p;        p += (size_t)E * 2;                 // 3.2MB
    int* ghist  = (int*)p;                p += (size_t)2 * NBUK * NCH * 4;    // 2.45MB
    int* gstart = (int*)p;                p += (size_t)2 * NBUK * NCH * 4;    // 2.45MB
    int* bstart = (int*)p;                p += (size_t)2 * NBUK * 4;
    int* off0   = (int*)p;                p += (size_t)(NN + 1) * 4;
    int* off1   = (int*)p;                p += (size_t)(NN + 1) * 4;
    int* perm0  = (int*)p;                p += (size_t)NN * 4;
    int* perm1  = (int*)p;                p += (size_t)NN * 4;
    int* dbin   = (int*)p;                p += (size_t)2 * DEGB * 4;
    int* dcur   = (int*)p;                p += (size_t)2 * DEGB * 4;
    p = (char*)(((uintptr_t)p + 15) & ~(uintptr_t)15);
    int* gchunk0 = (int*)p;                                                   // NCH*CHSZ ints
    int* gchunk1 = gchunk0 + (size_t)NCH * CHSZ;
    __half2* lgh = (__half2*)gchunk0;     // fp16 logits alias gchunk (dead by agg_b), 12.8MB

    hipMemsetAsync(dbin, 0, 2 * DEGB * sizeof(int), stream);
    fat_k<<<nsort + gemmb, 256, 0, stream>>>(X, W, xs, nodes, hedges,
                                             gchunk0, gchunk1, ghist, gstart, E, NCH, nsort);
    bucketbase_k<<<2, 1024, 0, stream>>>(ghist, bstart, off0, off1, E, NCH);
    merge_scatter_k<<<2 * NBUK, 256, 0, stream>>>(gchunk0, gchunk1, ghist, gstart, bstart,
                                                  adj0, adj1, off0, off1, NCH);
    deghist_k<<<(2 * NN + 255) / 256, 256, 0, stream>>>(off0, off1, dbin);
    degscan_k<<<1, 256, 0, stream>>>(dbin, dcur);
    degfill_k<<<(2 * NN + 255) / 256, 256, 0, stream>>>(off0, off1, dcur, perm0, perm1);
    agg_a_k<<<8 * ((NM + 127) / 128), 256, 0, stream>>>(xs, adj0, off0, perm0, ms);
    agg_b_k<<<8 * ((NN + 127) / 128), 256, 0, stream>>>(ms, adj1, off1, perm1, b, lgh);
    softmax_k<<<NN / 4, 256, 0, stream>>>(lgh, (float2*)d_out);
}

// Round 8
// 315.544 us; speedup vs baseline: 1.7851x; 1.7851x over previous
//
#include <hip/hip_runtime.h>
#include <hip/hip_fp16.h>

#define NN 50000
#define NM 50000
#define F  128
#define NBUK 782      // ceil(50000/64) buckets of 64 dest ids
#define CHSZ 8192     // edges per sort chunk
#define GROWS 12      // gemm rows per block
#define DEGB 256      // degree bins for segment sort
#define DSB  1024     // segments per degree-sort block
#define NDB  ((NN + DSB - 1) / DSB)   // 49
typedef unsigned short ushort_t;

union HF4 { float4 f4; __half2 h2[4]; };

// ---------------- block-scan helpers ---------------------------------------------
__device__ __forceinline__ int wscan64(int v, int lane) {
    int x = v;
#pragma unroll
    for (int s = 1; s < 64; s <<= 1) {
        int u = __shfl_up(x, s, 64);
        if (lane >= s) x += u;
    }
    return x;   // inclusive
}

__device__ __forceinline__ int bscan256(int v, int* s5, int* tot) {
    int t = threadIdx.x, lane = t & 63, wid = t >> 6;
    int incl = wscan64(v, lane);
    if (lane == 63) s5[wid] = incl;
    __syncthreads();
    if (t == 0) {
        int a = 0;
#pragma unroll
        for (int j = 0; j < 4; ++j) { int x = s5[j]; s5[j] = a; a += x; }
        s5[4] = a;
    }
    __syncthreads();
    int ex = incl - v + s5[wid];
    *tot = s5[4];
    __syncthreads();
    return ex;
}

// ---------------- fat kernel: chunksort blocks [0,nsort) + gemm blocks -----------
struct GemmSmem { __half sWh[128 * 128]; float sX[GROWS * 128]; };   // 32KB + 6KB
struct SortSmem { int hist[NBUK]; int cursor[NBUK]; int pairs[CHSZ]; int s5[5]; }; // 39KB
union alignas(16) FatSmem { GemmSmem g; SortSmem s; };

__global__ __launch_bounds__(256) void fat_k(const float* __restrict__ X,
                                             const float* __restrict__ W,
                                             __half2* __restrict__ xs,     // sliced x table
                                             const int* __restrict__ nodes,
                                             const int* __restrict__ hedges,
                                             int* __restrict__ gchunk0, int* __restrict__ gchunk1,
                                             int* __restrict__ ghist, int* __restrict__ gstart,
                                             int E, int NCH, int nsort) {
    __shared__ FatSmem u;
    int t = threadIdx.x;

    if ((int)blockIdx.x < nsort) {
        // ---------------- chunksort ----------------
        int dir = blockIdx.x / NCH;
        int c   = blockIdx.x % NCH;
        const int* key = dir ? nodes  : hedges;
        const int* pay = dir ? hedges : nodes;
        int* gchunk    = dir ? gchunk1 : gchunk0;
        int e0 = c * CHSZ, e1 = min(E, e0 + CHSZ);

        for (int i = t; i < NBUK; i += 256) u.s.hist[i] = 0;
        __syncthreads();
        for (int e = e0 + t; e < e1; e += 256) atomicAdd(&u.s.hist[key[e] >> 6], 1);
        __syncthreads();

        int carry = 0;
        for (int base = 0; base < NBUK; base += 256) {
            int i = base + t;
            int v = (i < NBUK) ? u.s.hist[i] : 0;
            int tot;
            int ex = bscan256(v, u.s.s5, &tot);
            if (i < NBUK) u.s.cursor[i] = ex + carry;
            carry += tot;
        }
        __syncthreads();

        for (int b = t; b < NBUK; b += 256) {
            size_t idx = ((size_t)dir * NBUK + b) * NCH + c;
            ghist[idx]  = u.s.hist[b];
            gstart[idx] = u.s.cursor[b];
        }
        __syncthreads();

        for (int e = e0 + t; e < e1; e += 256) {
            int k = key[e];
            int pos = atomicAdd(&u.s.cursor[k >> 6], 1);
            u.s.pairs[pos] = ((k & 63) << 16) | pay[e];
        }
        __syncthreads();

        int n = e1 - e0;
        for (int i = t; i < n; i += 256) gchunk[(size_t)c * CHSZ + i] = u.s.pairs[i];
    } else {
        // ---------------- gemm: x = X @ W -> fp16 sliced table ----------------
        int gb = blockIdx.x - nsort;

        __half2* sWh2 = (__half2*)u.g.sWh;
        for (int i = t; i < 4096; i += 256) {
            float4 wv = ((const float4*)W)[i];
            int k = i >> 5, cc = i & 31;
            sWh2[k * 64 + 2 * cc]     = __floats2half2_rn(wv.x, wv.y);
            sWh2[k * 64 + 2 * cc + 1] = __floats2half2_rn(wv.z, wv.w);
        }
        const float4* X4 = (const float4*)X;
        size_t gbase = (size_t)gb * GROWS * 32;
        for (int i = t; i < GROWS * 32; i += 256) {
            size_t gi = gbase + i;
            ((float4*)u.g.sX)[i] = (gi < (size_t)NN * 32) ? X4[gi] : make_float4(0.f, 0.f, 0.f, 0.f);
        }
        __syncthreads();

        int l = t & 63, w = t >> 6;           // lane owns col pair (2l,2l+1); wave owns 3 rows
        float acc[3][2] = {};
        for (int k0 = 0; k0 < 128; k0 += 4) {
            float4 xr0 = *(const float4*)&u.g.sX[(w * 3 + 0) * 128 + k0];
            float4 xr1 = *(const float4*)&u.g.sX[(w * 3 + 1) * 128 + k0];
            float4 xr2 = *(const float4*)&u.g.sX[(w * 3 + 2) * 128 + k0];
            const float* x0 = (const float*)&xr0;
            const float* x1 = (const float*)&xr1;
            const float* x2p = (const float*)&xr2;
#pragma unroll
            for (int j = 0; j < 4; ++j) {
                float2 wv = __half22float2(sWh2[(k0 + j) * 64 + l]);
                acc[0][0] = fmaf(x0[j], wv.x, acc[0][0]); acc[0][1] = fmaf(x0[j], wv.y, acc[0][1]);
                acc[1][0] = fmaf(x1[j], wv.x, acc[1][0]); acc[1][1] = fmaf(x1[j], wv.y, acc[1][1]);
                acc[2][0] = fmaf(x2p[j], wv.x, acc[2][0]); acc[2][1] = fmaf(x2p[j], wv.y, acc[2][1]);
            }
        }
        int s = l >> 3, cc = l & 7;           // slice, half2-col within slice
#pragma unroll
        for (int r = 0; r < 3; ++r) {
            int row = gb * GROWS + w * 3 + r;
            if (row < NN)
                xs[((size_t)s * NN + row) * 8 + cc] = __floats2half2_rn(acc[r][0], acc[r][1]);
        }
    }
}

// ---------------- 2: bucket totals -> global bucket starts -----------------------
__global__ __launch_bounds__(1024) void bucketbase_k(const int* __restrict__ ghist,
                                                     int* __restrict__ bstart,
                                                     int* __restrict__ off0, int* __restrict__ off1,
                                                     int E, int NCH) {
    __shared__ int s16[17];
    int dir = blockIdx.x;
    int t = threadIdx.x, lane = t & 63, wid = t >> 6;
    int v = 0;
    if (t < NBUK) {
        const int* row = ghist + ((size_t)dir * NBUK + t) * NCH;
        int s = 0;
#pragma unroll 4
        for (int c = 0; c < NCH; ++c) s += row[c];
        v = s;
    }
    int incl = wscan64(v, lane);
    if (lane == 63) s16[wid] = incl;
    __syncthreads();
    if (t < 16) {
        int x = s16[t], y = x;
#pragma unroll
        for (int s = 1; s < 16; s <<= 1) {
            int u = __shfl_up(y, s, 64);
            if (t >= s) y += u;
        }
        s16[t] = y - x;
    }
    __syncthreads();
    int ex = incl - v + s16[wid];
    if (t < NBUK) bstart[dir * NBUK + t] = ex;
    if (t == 0) (dir ? off1 : off0)[50000] = E;
}

// ---------------- 3: per-bucket merge + fine sort + scatter ----------------------
__global__ __launch_bounds__(256) void merge_scatter_k(const int* __restrict__ gchunk0, const int* __restrict__ gchunk1,
                                                       const int* __restrict__ ghist, const int* __restrict__ gstart,
                                                       const int* __restrict__ bstart,
                                                       ushort_t* __restrict__ adj0, ushort_t* __restrict__ adj1,
                                                       int* __restrict__ off0, int* __restrict__ off1,
                                                       int NCH) {
    __shared__ int ssrc[256];
    __shared__ int sdst[257];
    __shared__ int s5[5];
    __shared__ int pairsS[CHSZ];
    __shared__ int fcnt[64], foff[64], fcur[64];

    int dir = blockIdx.x / NBUK;
    int b   = blockIdx.x % NBUK;
    int t   = threadIdx.x;
    const int* gchunk   = dir ? gchunk1 : gchunk0;
    ushort_t* adj       = dir ? adj1 : adj0;
    int* offD           = dir ? off1 : off0;

    int len = 0, src = 0;
    if (t < NCH) {
        size_t idx = ((size_t)dir * NBUK + b) * NCH + t;
        len = ghist[idx];
        src = gstart[idx];
    }
    ssrc[t] = src;
    int tot;
    int ex = bscan256(len, s5, &tot);
    sdst[t] = ex;
    if (t == 0) sdst[256] = 0x7FFFFFFF;
    if (t < 64) fcnt[t] = 0;
    __syncthreads();
    int T = tot;

    int per = (T + 255) >> 8;
    int i0 = t * per, i1 = min(T, i0 + per);
    if (i0 < i1) {
        int lo = 0, hi = 255;
        while (lo < hi) {
            int mid = (lo + hi + 1) >> 1;
            if (sdst[mid] <= i0) lo = mid; else hi = mid - 1;
        }
        int c = lo;
        for (int i = i0; i < i1; ++i) {
            while (c < 255 && sdst[c + 1] <= i) ++c;
            int p = gchunk[(size_t)c * CHSZ + ssrc[c] + (i - sdst[c])];
            pairsS[i] = p;
            atomicAdd(&fcnt[p >> 16], 1);
        }
    }
    __syncthreads();

    int bst = bstart[dir * NBUK + b];
    if (t < 64) {
        int x = fcnt[t];
        int y = wscan64(x, t);
        foff[t] = y - x;
        fcur[t] = y - x;
        int d = b * 64 + t;
        if (d < 50000) offD[d] = bst + foff[t];
    }
    __syncthreads();

    for (int i = t; i < T; i += 256) {
        int p = pairsS[i];
        int slot = atomicAdd(&fcur[p >> 16], 1);
        adj[(size_t)bst + slot] = (ushort_t)(p & 0xFFFF);
    }
}

// ---------------- degree-sort P1: per-block LDS histogram (no global atomics) ----
__global__ __launch_bounds__(256) void deghistA_k(const int* __restrict__ off0,
                                                  const int* __restrict__ off1,
                                                  int* __restrict__ blockhist) {
    __shared__ int h[DEGB];
    int dir = blockIdx.x / NDB, blk = blockIdx.x % NDB;
    const int* off = dir ? off1 : off0;
    int t = threadIdx.x;
    h[t] = 0;
    __syncthreads();
    int s0 = blk * DSB, s1 = min(NN, s0 + DSB);
    for (int s = s0 + t; s < s1; s += 256) {
        int d = min(off[s + 1] - off[s], DEGB - 1);
        atomicAdd(&h[d], 1);
    }
    __syncthreads();
    blockhist[((size_t)dir * DEGB + t) * NDB + blk] = h[t];
}

// ---------------- degree-sort P2: scan -> per-(bin,blk) global bases in place ----
__global__ __launch_bounds__(256) void deghistB_k(int* __restrict__ blockhist) {
    __shared__ int s5[5];
    int dir = blockIdx.x;
    int t = threadIdx.x;    // = bin
    int* row = blockhist + ((size_t)dir * DEGB + t) * NDB;
    int sum = 0;
#pragma unroll 7
    for (int b = 0; b < NDB; ++b) sum += row[b];
    int tot;
    int binbase = bscan256(sum, s5, &tot);   // exclusive over bins
    int run = binbase;
    for (int b = 0; b < NDB; ++b) { int v = row[b]; row[b] = run; run += v; }
}

// ---------------- degree-sort P3: fill perm via LDS cursors ----------------------
__global__ __launch_bounds__(256) void degfill_k(const int* __restrict__ off0,
                                                 const int* __restrict__ off1,
                                                 const int* __restrict__ blockhist,
                                                 int* __restrict__ perm0, int* __restrict__ perm1) {
    __shared__ int cur[DEGB];
    int dir = blockIdx.x / NDB, blk = blockIdx.x % NDB;
    const int* off = dir ? off1 : off0;
    int* perm = dir ? perm1 : perm0;
    int t = threadIdx.x;
    cur[t] = blockhist[((size_t)dir * DEGB + t) * NDB + blk];
    __syncthreads();
    int s0 = blk * DSB, s1 = min(NN, s0 + DSB);
    for (int s = s0 + t; s < s1; s += 256) {
        int d = min(off[s + 1] - off[s], DEGB - 1);
        int pos = atomicAdd(&cur[d], 1);
        perm[pos] = s;
    }
}

// ---------------- pass A (sliced, sorted, G=2): m_s[h] = B_inv * sum x_s[v] ------
__global__ __launch_bounds__(256) void agg_a_k(const __half2* __restrict__ xs,
                                               const ushort_t* __restrict__ adj,
                                               const int* __restrict__ off,
                                               const int* __restrict__ perm,
                                               __half2* __restrict__ ms) {
    int t = threadIdx.x;
    int s = blockIdx.x & 7;
    int gi = (blockIdx.x >> 3) * 128 + (t >> 1);
    int c2 = t & 1;
    if (gi >= NM) return;
    int seg = perm[gi];
    int p0 = off[seg], p1 = off[seg + 1];
    const __half2* base = xs + (size_t)s * NN * 8 + c2 * 4;
    float a0 = 0.f, a1 = 0.f, a2 = 0.f, a3 = 0.f, a4 = 0.f, a5 = 0.f, a6 = 0.f, a7 = 0.f;
    int i = p0;
    for (; i + 4 <= p1; i += 4) {
        int n0 = adj[i], n1 = adj[i + 1], n2 = adj[i + 2], n3 = adj[i + 3];
        HF4 u0, u1, u2, u3;
        u0.f4 = *(const float4*)(base + (size_t)n0 * 8);
        u1.f4 = *(const float4*)(base + (size_t)n1 * 8);
        u2.f4 = *(const float4*)(base + (size_t)n2 * 8);
        u3.f4 = *(const float4*)(base + (size_t)n3 * 8);
#pragma unroll
        for (int k = 0; k < 4; ++k) {
            float2 f0 = __half22float2(u0.h2[k]);
            float2 f1 = __half22float2(u1.h2[k]);
            float2 f2 = __half22float2(u2.h2[k]);
            float2 f3 = __half22float2(u3.h2[k]);
            float sx = (f0.x + f1.x) + (f2.x + f3.x);
            float sy = (f0.y + f1.y) + (f2.y + f3.y);
            if (k == 0) { a0 += sx; a1 += sy; }
            else if (k == 1) { a2 += sx; a3 += sy; }
            else if (k == 2) { a4 += sx; a5 += sy; }
            else { a6 += sx; a7 += sy; }
        }
    }
    for (; i < p1; ++i) {
        HF4 u0;
        u0.f4 = *(const float4*)(base + (size_t)adj[i] * 8);
        float2 f;
        f = __half22float2(u0.h2[0]); a0 += f.x; a1 += f.y;
        f = __half22float2(u0.h2[1]); a2 += f.x; a3 += f.y;
        f = __half22float2(u0.h2[2]); a4 += f.x; a5 += f.y;
        f = __half22float2(u0.h2[3]); a6 += f.x; a7 += f.y;
    }
    float inv = (p1 > p0) ? 1.0f / (float)(p1 - p0) : 0.0f;
    HF4 w;
    w.h2[0] = __floats2half2_rn(a0 * inv, a1 * inv);
    w.h2[1] = __floats2half2_rn(a2 * inv, a3 * inv);
    w.h2[2] = __floats2half2_rn(a4 * inv, a5 * inv);
    w.h2[3] = __floats2half2_rn(a6 * inv, a7 * inv);
    *(float4*)(ms + ((size_t)s * NM + seg) * 8 + c2 * 4) = w.f4;
}

// ---------------- pass B (sliced, sorted, G=2): logits -> fp16 -------------------
__global__ __launch_bounds__(256) void agg_b_k(const __half2* __restrict__ ms,
                                               const ushort_t* __restrict__ adj,
                                               const int* __restrict__ off,
                                               const int* __restrict__ perm,
                                               const float* __restrict__ bias,
                                               __half2* __restrict__ lgh) {
    int t = threadIdx.x;
    int s = blockIdx.x & 7;
    int gi = (blockIdx.x >> 3) * 128 + (t >> 1);
    int c2 = t & 1;
    if (gi >= NN) return;
    int seg = perm[gi];
    int p0 = off[seg], p1 = off[seg + 1];
    const __half2* base = ms + (size_t)s * NM * 8 + c2 * 4;
    float a0 = 0.f, a1 = 0.f, a2 = 0.f, a3 = 0.f, a4 = 0.f, a5 = 0.f, a6 = 0.f, a7 = 0.f;
    int i = p0;
    for (; i + 4 <= p1; i += 4) {
        int n0 = adj[i], n1 = adj[i + 1], n2 = adj[i + 2], n3 = adj[i + 3];
        HF4 u0, u1, u2, u3;
        u0.f4 = *(const float4*)(base + (size_t)n0 * 8);
        u1.f4 = *(const float4*)(base + (size_t)n1 * 8);
        u2.f4 = *(const float4*)(base + (size_t)n2 * 8);
        u3.f4 = *(const float4*)(base + (size_t)n3 * 8);
#pragma unroll
        for (int k = 0; k < 4; ++k) {
            float2 f0 = __half22float2(u0.h2[k]);
            float2 f1 = __half22float2(u1.h2[k]);
            float2 f2 = __half22float2(u2.h2[k]);
            float2 f3 = __half22float2(u3.h2[k]);
            float sx = (f0.x + f1.x) + (f2.x + f3.x);
            float sy = (f0.y + f1.y) + (f2.y + f3.y);
            if (k == 0) { a0 += sx; a1 += sy; }
            else if (k == 1) { a2 += sx; a3 += sy; }
            else if (k == 2) { a4 += sx; a5 += sy; }
            else { a6 += sx; a7 += sy; }
        }
    }
    for (; i < p1; ++i) {
        HF4 u0;
        u0.f4 = *(const float4*)(base + (size_t)adj[i] * 8);
        float2 f;
        f = __half22float2(u0.h2[0]); a0 += f.x; a1 += f.y;
        f = __half22float2(u0.h2[1]); a2 += f.x; a3 += f.y;
        f = __half22float2(u0.h2[2]); a4 += f.x; a5 += f.y;
        f = __half22float2(u0.h2[3]); a6 += f.x; a7 += f.y;
    }
    float inv = (p1 > p0) ? 1.0f / (float)(p1 - p0) : 0.0f;
    const float2* bias2 = (const float2*)bias;
    float2 b0 = bias2[s * 8 + c2 * 4];
    float2 b1 = bias2[s * 8 + c2 * 4 + 1];
    float2 b2 = bias2[s * 8 + c2 * 4 + 2];
    float2 b3 = bias2[s * 8 + c2 * 4 + 3];
    HF4 w;
    w.h2[0] = __floats2half2_rn(a0 * inv + b0.x, a1 * inv + b0.y);
    w.h2[1] = __floats2half2_rn(a2 * inv + b1.x, a3 * inv + b1.y);
    w.h2[2] = __floats2half2_rn(a4 * inv + b2.x, a5 * inv + b2.y);
    w.h2[3] = __floats2half2_rn(a6 * inv + b3.x, a7 * inv + b3.y);
    *(float4*)(lgh + ((size_t)s * NN + seg) * 8 + c2 * 4) = w.f4;
}

// ---------------- final: row softmax from sliced fp16 logits -> d_out ------------
__global__ __launch_bounds__(256) void softmax_k(const __half2* __restrict__ lgh,
                                                 float2* __restrict__ out) {
    int v = blockIdx.x * 4 + (threadIdx.x >> 6);
    int l = threadIdx.x & 63;
    float2 val = __half22float2(lgh[((size_t)(l >> 3) * NN + v) * 8 + (l & 7)]);
    float mx = fmaxf(val.x, val.y);
#pragma unroll
    for (int s2 = 32; s2 >= 1; s2 >>= 1) mx = fmaxf(mx, __shfl_xor(mx, s2, 64));
    float e0 = __expf(val.x - mx), e1 = __expf(val.y - mx);
    float sm = e0 + e1;
#pragma unroll
    for (int s2 = 32; s2 >= 1; s2 >>= 1) sm += __shfl_xor(sm, s2, 64);
    float r = 1.0f / sm;
    out[(size_t)v * 64 + l] = make_float2(e0 * r, e1 * r);
}

// ---------------- launcher -------------------------------------------------------
extern "C" void kernel_launch(void* const* d_in, const int* in_sizes, int n_in,
                              void* d_out, int out_size, void* d_ws, size_t ws_size,
                              hipStream_t stream) {
    const float* X  = (const float*)d_in[0];
    const int*   ei = (const int*)d_in[1];
    const float* W  = (const float*)d_in[2];
    const float* b  = (const float*)d_in[3];

    int E = in_sizes[1] / 2;
    const int* nodes  = ei;
    const int* hedges = ei + E;
    int NCH = (E + CHSZ - 1) / CHSZ;       // 196 for E=1.6M (must be <= 256)
    int nsort = 2 * NCH;
    int gemmb = (NN + GROWS - 1) / GROWS;

    // workspace layout (~62 MB)
    char* p = (char*)d_ws;
    __half2* xs = (__half2*)p;            p += (size_t)NN * F * 2;            // sliced x, 12.8MB
    __half2* ms = (__half2*)p;            p += (size_t)NM * F * 2;            // sliced m, 12.8MB
    ushort_t* adj0 = (ushort_t*)p;        p += (size_t)E * 2;                 // 3.2MB
    ushort_t* adj1 = (ushort_t*)p;        p += (size_t)E * 2;                 // 3.2MB
    int* ghist  = (int*)p;                p += (size_t)2 * NBUK * NCH * 4;    // 2.45MB
    int* gstart = (int*)p;                p += (size_t)2 * NBUK * NCH * 4;    // 2.45MB
    int* bstart = (int*)p;                p += (size_t)2 * NBUK * 4;
    int* off0   = (int*)p;                p += (size_t)(NN + 1) * 4;
    int* off1   = (int*)p;                p += (size_t)(NN + 1) * 4;
    int* perm0  = (int*)p;                p += (size_t)NN * 4;
    int* perm1  = (int*)p;                p += (size_t)NN * 4;
    int* blockhist = (int*)p;             p += (size_t)2 * DEGB * NDB * 4;    // 100KB
    p = (char*)(((uintptr_t)p + 15) & ~(uintptr_t)15);
    int* gchunk0 = (int*)p;                                                   // NCH*CHSZ ints
    int* gchunk1 = gchunk0 + (size_t)NCH * CHSZ;
    __half2* lgh = (__half2*)gchunk0;     // fp16 logits alias gchunk (dead by agg_b), 12.8MB

    fat_k<<<nsort + gemmb, 256, 0, stream>>>(X, W, xs, nodes, hedges,
                                             gchunk0, gchunk1, ghist, gstart, E, NCH, nsort);
    bucketbase_k<<<2, 1024, 0, stream>>>(ghist, bstart, off0, off1, E, NCH);
    merge_scatter_k<<<2 * NBUK, 256, 0, stream>>>(gchunk0, gchunk1, ghist, gstart, bstart,
                                                  adj0, adj1, off0, off1, NCH);
    deghistA_k<<<2 * NDB, 256, 0, stream>>>(off0, off1, blockhist);
    deghistB_k<<<2, 256, 0, stream>>>(blockhist);
    degfill_k<<<2 * NDB, 256, 0, stream>>>(off0, off1, blockhist, perm0, perm1);
    agg_a_k<<<8 * ((NM + 127) / 128), 256, 0, stream>>>(xs, adj0, off0, perm0, ms);
    agg_b_k<<<8 * ((NN + 127) / 128), 256, 0, stream>>>(ms, adj1, off1, perm1, b, lgh);
    softmax_k<<<NN / 4, 256, 0, stream>>>(lgh, (float2*)d_out);
}

// Round 9
// 235.196 us; speedup vs baseline: 2.3950x; 1.3416x over previous
//
#include <hip/hip_runtime.h>
#include <hip/hip_fp16.h>

#define NN 50000
#define NM 50000
#define F  128
#define NBUK 782      // ceil(50000/64) buckets of 64 dest ids
#define CHSZ 8192     // edges per sort chunk
#define GROWS 12      // gemm rows per block
typedef unsigned short ushort_t;

union HF4 { float4 f4; __half2 h2[4]; };

// ---------------- block-scan helpers ---------------------------------------------
__device__ __forceinline__ int wscan64(int v, int lane) {
    int x = v;
#pragma unroll
    for (int s = 1; s < 64; s <<= 1) {
        int u = __shfl_up(x, s, 64);
        if (lane >= s) x += u;
    }
    return x;   // inclusive
}

__device__ __forceinline__ int bscan256(int v, int* s5, int* tot) {
    int t = threadIdx.x, lane = t & 63, wid = t >> 6;
    int incl = wscan64(v, lane);
    if (lane == 63) s5[wid] = incl;
    __syncthreads();
    if (t == 0) {
        int a = 0;
#pragma unroll
        for (int j = 0; j < 4; ++j) { int x = s5[j]; s5[j] = a; a += x; }
        s5[4] = a;
    }
    __syncthreads();
    int ex = incl - v + s5[wid];
    *tot = s5[4];
    __syncthreads();
    return ex;
}

// ---------------- fat kernel: chunksort blocks [0,nsort) + gemm blocks -----------
struct GemmSmem { __half sWh[128 * 128]; float sX[GROWS * 128]; };   // 32KB + 6KB
struct SortSmem { int hist[NBUK]; int cursor[NBUK]; int pairs[CHSZ]; int s5[5]; }; // 39KB
union alignas(16) FatSmem { GemmSmem g; SortSmem s; };

__global__ __launch_bounds__(256) void fat_k(const float* __restrict__ X,
                                             const float* __restrict__ W,
                                             __half2* __restrict__ xs,     // row-major [NN][64] half2
                                             const int* __restrict__ nodes,
                                             const int* __restrict__ hedges,
                                             int* __restrict__ gchunk0, int* __restrict__ gchunk1,
                                             int* __restrict__ ghist, int* __restrict__ gstart,
                                             int E, int NCH, int nsort) {
    __shared__ FatSmem u;
    int t = threadIdx.x;

    if ((int)blockIdx.x < nsort) {
        // ---------------- chunksort ----------------
        int dir = blockIdx.x / NCH;
        int c   = blockIdx.x % NCH;
        const int* key = dir ? nodes  : hedges;
        const int* pay = dir ? hedges : nodes;
        int* gchunk    = dir ? gchunk1 : gchunk0;
        int e0 = c * CHSZ, e1 = min(E, e0 + CHSZ);

        for (int i = t; i < NBUK; i += 256) u.s.hist[i] = 0;
        __syncthreads();
        for (int e = e0 + t; e < e1; e += 256) atomicAdd(&u.s.hist[key[e] >> 6], 1);
        __syncthreads();

        int carry = 0;
        for (int base = 0; base < NBUK; base += 256) {
            int i = base + t;
            int v = (i < NBUK) ? u.s.hist[i] : 0;
            int tot;
            int ex = bscan256(v, u.s.s5, &tot);
            if (i < NBUK) u.s.cursor[i] = ex + carry;
            carry += tot;
        }
        __syncthreads();

        for (int b = t; b < NBUK; b += 256) {
            size_t idx = ((size_t)dir * NBUK + b) * NCH + c;
            ghist[idx]  = u.s.hist[b];
            gstart[idx] = u.s.cursor[b];
        }
        __syncthreads();

        for (int e = e0 + t; e < e1; e += 256) {
            int k = key[e];
            int pos = atomicAdd(&u.s.cursor[k >> 6], 1);
            u.s.pairs[pos] = ((k & 63) << 16) | pay[e];
        }
        __syncthreads();

        int n = e1 - e0;
        for (int i = t; i < n; i += 256) gchunk[(size_t)c * CHSZ + i] = u.s.pairs[i];
    } else {
        // ---------------- gemm: x = X @ W -> fp16 row-major ----------------
        int gb = blockIdx.x - nsort;

        __half2* sWh2 = (__half2*)u.g.sWh;   // sWh2[k*64+l] = (W[k][2l], W[k][2l+1])
        for (int i = t; i < 4096; i += 256) {
            float4 wv = ((const float4*)W)[i];
            int k = i >> 5, cc = i & 31;
            sWh2[k * 64 + 2 * cc]     = __floats2half2_rn(wv.x, wv.y);
            sWh2[k * 64 + 2 * cc + 1] = __floats2half2_rn(wv.z, wv.w);
        }
        const float4* X4 = (const float4*)X;
        size_t gbase = (size_t)gb * GROWS * 32;
        for (int i = t; i < GROWS * 32; i += 256) {
            size_t gi = gbase + i;
            ((float4*)u.g.sX)[i] = (gi < (size_t)NN * 32) ? X4[gi] : make_float4(0.f, 0.f, 0.f, 0.f);
        }
        __syncthreads();

        int l = t & 63, w = t >> 6;           // lane owns col pair (2l,2l+1); wave owns 3 rows
        float acc[3][2] = {};
        for (int k0 = 0; k0 < 128; k0 += 4) {
            float4 xr0 = *(const float4*)&u.g.sX[(w * 3 + 0) * 128 + k0];
            float4 xr1 = *(const float4*)&u.g.sX[(w * 3 + 1) * 128 + k0];
            float4 xr2 = *(const float4*)&u.g.sX[(w * 3 + 2) * 128 + k0];
            const float* x0 = (const float*)&xr0;
            const float* x1 = (const float*)&xr1;
            const float* x2p = (const float*)&xr2;
#pragma unroll
            for (int j = 0; j < 4; ++j) {
                float2 wv = __half22float2(sWh2[(k0 + j) * 64 + l]);
                acc[0][0] = fmaf(x0[j], wv.x, acc[0][0]); acc[0][1] = fmaf(x0[j], wv.y, acc[0][1]);
                acc[1][0] = fmaf(x1[j], wv.x, acc[1][0]); acc[1][1] = fmaf(x1[j], wv.y, acc[1][1]);
                acc[2][0] = fmaf(x2p[j], wv.x, acc[2][0]); acc[2][1] = fmaf(x2p[j], wv.y, acc[2][1]);
            }
        }
#pragma unroll
        for (int r = 0; r < 3; ++r) {
            int row = gb * GROWS + w * 3 + r;
            if (row < NN)
                xs[(size_t)row * 64 + l] = __floats2half2_rn(acc[r][0], acc[r][1]);
        }
    }
}

// ---------------- 2: bucket totals -> global bucket starts -----------------------
__global__ __launch_bounds__(1024) void bucketbase_k(const int* __restrict__ ghist,
                                                     int* __restrict__ bstart,
                                                     int* __restrict__ off0, int* __restrict__ off1,
                                                     int E, int NCH) {
    __shared__ int s16[17];
    int dir = blockIdx.x;
    int t = threadIdx.x, lane = t & 63, wid = t >> 6;
    int v = 0;
    if (t < NBUK) {
        const int* row = ghist + ((size_t)dir * NBUK + t) * NCH;
        int s = 0;
#pragma unroll 4
        for (int c = 0; c < NCH; ++c) s += row[c];
        v = s;
    }
    int incl = wscan64(v, lane);
    if (lane == 63) s16[wid] = incl;
    __syncthreads();
    if (t < 16) {
        int x = s16[t], y = x;
#pragma unroll
        for (int s = 1; s < 16; s <<= 1) {
            int u = __shfl_up(y, s, 64);
            if (t >= s) y += u;
        }
        s16[t] = y - x;
    }
    __syncthreads();
    int ex = incl - v + s16[wid];
    if (t < NBUK) bstart[dir * NBUK + t] = ex;
    if (t == 0) (dir ? off1 : off0)[50000] = E;
}

// ---------------- 3: per-bucket merge + fine sort + scatter ----------------------
__global__ __launch_bounds__(256) void merge_scatter_k(const int* __restrict__ gchunk0, const int* __restrict__ gchunk1,
                                                       const int* __restrict__ ghist, const int* __restrict__ gstart,
                                                       const int* __restrict__ bstart,
                                                       ushort_t* __restrict__ adj0, ushort_t* __restrict__ adj1,
                                                       int* __restrict__ off0, int* __restrict__ off1,
                                                       int NCH) {
    __shared__ int ssrc[256];
    __shared__ int sdst[257];
    __shared__ int s5[5];
    __shared__ int pairsS[CHSZ];
    __shared__ int fcnt[64], foff[64], fcur[64];

    int dir = blockIdx.x / NBUK;
    int b   = blockIdx.x % NBUK;
    int t   = threadIdx.x;
    const int* gchunk   = dir ? gchunk1 : gchunk0;
    ushort_t* adj       = dir ? adj1 : adj0;
    int* offD           = dir ? off1 : off0;

    int len = 0, src = 0;
    if (t < NCH) {
        size_t idx = ((size_t)dir * NBUK + b) * NCH + t;
        len = ghist[idx];
        src = gstart[idx];
    }
    ssrc[t] = src;
    int tot;
    int ex = bscan256(len, s5, &tot);
    sdst[t] = ex;
    if (t == 0) sdst[256] = 0x7FFFFFFF;
    if (t < 64) fcnt[t] = 0;
    __syncthreads();
    int T = tot;

    int per = (T + 255) >> 8;
    int i0 = t * per, i1 = min(T, i0 + per);
    if (i0 < i1) {
        int lo = 0, hi = 255;
        while (lo < hi) {
            int mid = (lo + hi + 1) >> 1;
            if (sdst[mid] <= i0) lo = mid; else hi = mid - 1;
        }
        int c = lo;
        for (int i = i0; i < i1; ++i) {
            while (c < 255 && sdst[c + 1] <= i) ++c;
            int p = gchunk[(size_t)c * CHSZ + ssrc[c] + (i - sdst[c])];
            pairsS[i] = p;
            atomicAdd(&fcnt[p >> 16], 1);
        }
    }
    __syncthreads();

    int bst = bstart[dir * NBUK + b];
    if (t < 64) {
        int x = fcnt[t];
        int y = wscan64(x, t);
        foff[t] = y - x;
        fcur[t] = y - x;
        int d = b * 64 + t;
        if (d < 50000) offD[d] = bst + foff[t];
    }
    __syncthreads();

    for (int i = t; i < T; i += 256) {
        int p = pairsS[i];
        int slot = atomicAdd(&fcur[p >> 16], 1);
        adj[(size_t)bst + slot] = (ushort_t)(p & 0xFFFF);
    }
}

// ---------------- pass A: m[h] = B_inv[h] * sum_{v in h} x[v] --------------------
// 1 wave/segment; 16 lanes x 4 rows; float4 (16B) gathers; f32 accumulate.
__global__ __launch_bounds__(256) void agg_a_k(const float4* __restrict__ x4,
                                               const ushort_t* __restrict__ adj,
                                               const int* __restrict__ off,
                                               float4* __restrict__ m4) {
    int t = threadIdx.x;
    int seg = blockIdx.x * 4 + (t >> 6);
    int l = t & 63;
    int rg = l >> 4, cc = l & 15;
    int p0 = off[seg], p1 = off[seg + 1];
    float acc[8] = {};
    int i = p0;
    for (; i + 16 <= p1; i += 16) {
        int r0 = adj[i + rg], r1 = adj[i + 4 + rg], r2 = adj[i + 8 + rg], r3 = adj[i + 12 + rg];
        HF4 u0, u1, u2, u3;
        u0.f4 = x4[(size_t)r0 * 16 + cc];
        u1.f4 = x4[(size_t)r1 * 16 + cc];
        u2.f4 = x4[(size_t)r2 * 16 + cc];
        u3.f4 = x4[(size_t)r3 * 16 + cc];
#pragma unroll
        for (int k = 0; k < 4; ++k) {
            float2 f0 = __half22float2(u0.h2[k]);
            float2 f1 = __half22float2(u1.h2[k]);
            float2 f2 = __half22float2(u2.h2[k]);
            float2 f3 = __half22float2(u3.h2[k]);
            acc[2 * k]     += (f0.x + f1.x) + (f2.x + f3.x);
            acc[2 * k + 1] += (f0.y + f1.y) + (f2.y + f3.y);
        }
    }
    for (; i < p1; i += 4) {
        int r = i + rg;
        if (r < p1) {
            HF4 u;
            u.f4 = x4[(size_t)adj[r] * 16 + cc];
#pragma unroll
            for (int k = 0; k < 4; ++k) {
                float2 f = __half22float2(u.h2[k]);
                acc[2 * k] += f.x; acc[2 * k + 1] += f.y;
            }
        }
    }
#pragma unroll
    for (int k = 0; k < 8; ++k) {
        acc[k] += __shfl_xor(acc[k], 16, 64);
        acc[k] += __shfl_xor(acc[k], 32, 64);
    }
    if (l < 16) {
        float inv = (p1 > p0) ? 1.0f / (float)(p1 - p0) : 0.0f;
        HF4 w;
#pragma unroll
        for (int k = 0; k < 4; ++k)
            w.h2[k] = __floats2half2_rn(acc[2 * k] * inv, acc[2 * k + 1] * inv);
        m4[(size_t)seg * 16 + cc] = w.f4;
    }
}

// ---------------- pass B: out[v] = softmax(D_inv[v]*sum m[h] + b) (fused) --------
__global__ __launch_bounds__(256) void agg_b_k(const float4* __restrict__ m4,
                                               const ushort_t* __restrict__ adj,
                                               const int* __restrict__ off,
                                               const float* __restrict__ bias,
                                               float4* __restrict__ out4) {
    int t = threadIdx.x;
    int seg = blockIdx.x * 4 + (t >> 6);
    int l = t & 63;
    int rg = l >> 4, cc = l & 15;
    int p0 = off[seg], p1 = off[seg + 1];
    float acc[8] = {};
    int i = p0;
    for (; i + 16 <= p1; i += 16) {
        int r0 = adj[i + rg], r1 = adj[i + 4 + rg], r2 = adj[i + 8 + rg], r3 = adj[i + 12 + rg];
        HF4 u0, u1, u2, u3;
        u0.f4 = m4[(size_t)r0 * 16 + cc];
        u1.f4 = m4[(size_t)r1 * 16 + cc];
        u2.f4 = m4[(size_t)r2 * 16 + cc];
        u3.f4 = m4[(size_t)r3 * 16 + cc];
#pragma unroll
        for (int k = 0; k < 4; ++k) {
            float2 f0 = __half22float2(u0.h2[k]);
            float2 f1 = __half22float2(u1.h2[k]);
            float2 f2 = __half22float2(u2.h2[k]);
            float2 f3 = __half22float2(u3.h2[k]);
            acc[2 * k]     += (f0.x + f1.x) + (f2.x + f3.x);
            acc[2 * k + 1] += (f0.y + f1.y) + (f2.y + f3.y);
        }
    }
    for (; i < p1; i += 4) {
        int r = i + rg;
        if (r < p1) {
            HF4 u;
            u.f4 = m4[(size_t)adj[r] * 16 + cc];
#pragma unroll
            for (int k = 0; k < 4; ++k) {
                float2 f = __half22float2(u.h2[k]);
                acc[2 * k] += f.x; acc[2 * k + 1] += f.y;
            }
        }
    }
#pragma unroll
    for (int k = 0; k < 8; ++k) {
        acc[k] += __shfl_xor(acc[k], 16, 64);
        acc[k] += __shfl_xor(acc[k], 32, 64);
    }
    float inv = (p1 > p0) ? 1.0f / (float)(p1 - p0) : 0.0f;
    const float4* b4 = (const float4*)bias;
    float4 bb0 = b4[cc * 2], bb1 = b4[cc * 2 + 1];
    float lg[8];
    lg[0] = acc[0] * inv + bb0.x; lg[1] = acc[1] * inv + bb0.y;
    lg[2] = acc[2] * inv + bb0.z; lg[3] = acc[3] * inv + bb0.w;
    lg[4] = acc[4] * inv + bb1.x; lg[5] = acc[5] * inv + bb1.y;
    lg[6] = acc[6] * inv + bb1.z; lg[7] = acc[7] * inv + bb1.w;

    float mx = lg[0];
#pragma unroll
    for (int k = 1; k < 8; ++k) mx = fmaxf(mx, lg[k]);
#pragma unroll
    for (int s = 1; s < 16; s <<= 1) mx = fmaxf(mx, __shfl_xor(mx, s, 16));
    float e[8], sm = 0.f;
#pragma unroll
    for (int k = 0; k < 8; ++k) { e[k] = __expf(lg[k] - mx); sm += e[k]; }
#pragma unroll
    for (int s = 1; s < 16; s <<= 1) sm += __shfl_xor(sm, s, 16);
    float r = 1.0f / sm;
    if (l < 16) {
        out4[(size_t)seg * 32 + cc * 2]     = make_float4(e[0] * r, e[1] * r, e[2] * r, e[3] * r);
        out4[(size_t)seg * 32 + cc * 2 + 1] = make_float4(e[4] * r, e[5] * r, e[6] * r, e[7] * r);
    }
}

// ---------------- launcher -------------------------------------------------------
extern "C" void kernel_launch(void* const* d_in, const int* in_sizes, int n_in,
                              void* d_out, int out_size, void* d_ws, size_t ws_size,
                              hipStream_t stream) {
    const float* X  = (const float*)d_in[0];
    const int*   ei = (const int*)d_in[1];
    const float* W  = (const float*)d_in[2];
    const float* b  = (const float*)d_in[3];

    int E = in_sizes[1] / 2;
    const int* nodes  = ei;
    const int* hedges = ei + E;
    int NCH = (E + CHSZ - 1) / CHSZ;       // 196 for E=1.6M (must be <= 256)
    int nsort = 2 * NCH;
    int gemmb = (NN + GROWS - 1) / GROWS;

    // workspace layout (~50 MB)
    char* p = (char*)d_ws;
    __half2* xs = (__half2*)p;            p += (size_t)NN * F * 2;            // 12.8MB
    __half2* ms = (__half2*)p;            p += (size_t)NM * F * 2;            // 12.8MB
    ushort_t* adj0 = (ushort_t*)p;        p += (size_t)E * 2;                 // 3.2MB
    ushort_t* adj1 = (ushort_t*)p;        p += (size_t)E * 2;                 // 3.2MB
    int* ghist  = (int*)p;                p += (size_t)2 * NBUK * NCH * 4;    // 2.45MB
    int* gstart = (int*)p;                p += (size_t)2 * NBUK * NCH * 4;    // 2.45MB
    int* bstart = (int*)p;                p += (size_t)2 * NBUK * 4;
    int* off0   = (int*)p;                p += (size_t)(NN + 1) * 4;
    int* off1   = (int*)p;                p += (size_t)(NN + 1) * 4;
    p = (char*)(((uintptr_t)p + 15) & ~(uintptr_t)15);
    int* gchunk0 = (int*)p;                                                   // NCH*CHSZ ints
    int* gchunk1 = gchunk0 + (size_t)NCH * CHSZ;

    fat_k<<<nsort + gemmb, 256, 0, stream>>>(X, W, xs, nodes, hedges,
                                             gchunk0, gchunk1, ghist, gstart, E, NCH, nsort);
    bucketbase_k<<<2, 1024, 0, stream>>>(ghist, bstart, off0, off1, E, NCH);
    merge_scatter_k<<<2 * NBUK, 256, 0, stream>>>(gchunk0, gchunk1, ghist, gstart, bstart,
                                                  adj0, adj1, off0, off1, NCH);
    agg_a_k<<<NM / 4, 256, 0, stream>>>((const float4*)xs, adj0, off0, (float4*)ms);
    agg_b_k<<<NN / 4, 256, 0, stream>>>((const float4*)ms, adj1, off1, b, (float4*)d_out);
}

// Round 10
// 229.613 us; speedup vs baseline: 2.4532x; 1.0243x over previous
//
#include <hip/hip_runtime.h>
#include <hip/hip_fp16.h>

#define NN 50000
#define NM 50000
#define F  128
#define NBUK 782      // ceil(50000/64) buckets of 64 dest ids
#define CHSZ 8192     // edges per sort chunk
typedef unsigned short ushort_t;
typedef _Float16 f16;
typedef f16 f16x8 __attribute__((ext_vector_type(8)));
typedef float f32x4 __attribute__((ext_vector_type(4)));

union HF4 { float4 f4; __half2 h2[4]; };
union PK4 { uint2 u2; f16 h[4]; };

// ---------------- block-scan helpers ---------------------------------------------
__device__ __forceinline__ int wscan64(int v, int lane) {
    int x = v;
#pragma unroll
    for (int s = 1; s < 64; s <<= 1) {
        int u = __shfl_up(x, s, 64);
        if (lane >= s) x += u;
    }
    return x;   // inclusive
}

__device__ __forceinline__ int bscan256(int v, int* s5, int* tot) {
    int t = threadIdx.x, lane = t & 63, wid = t >> 6;
    int incl = wscan64(v, lane);
    if (lane == 63) s5[wid] = incl;
    __syncthreads();
    if (t == 0) {
        int a = 0;
#pragma unroll
        for (int j = 0; j < 4; ++j) { int x = s5[j]; s5[j] = a; a += x; }
        s5[4] = a;
    }
    __syncthreads();
    int ex = incl - v + s5[wid];
    *tot = s5[4];
    __syncthreads();
    return ex;
}

// ---------------- W prep: Wt[col][k] fp16 (B-fragment-friendly, L2-hot) ----------
__global__ __launch_bounds__(256) void wprep_k(const float* __restrict__ W,
                                               f16* __restrict__ Wt) {
    int i = blockIdx.x * 256 + threadIdx.x;   // 16384
    int k = i >> 7, c = i & 127;
    Wt[c * 128 + k] = (f16)W[i];
}

// ---------------- fat kernel: chunksort blocks [0,nsort) + MFMA-gemm blocks ------
struct GemmSmem { f16 sXh[64 * 128]; };                                            // 16KB
struct SortSmem { int hist[NBUK]; int cursor[NBUK]; int pairs[CHSZ]; int s5[5]; }; // 39.4KB
union alignas(16) FatSmem { GemmSmem g; SortSmem s; };

__global__ __launch_bounds__(256) void fat_k(const float* __restrict__ X,
                                             const f16* __restrict__ Wt,
                                             f16* __restrict__ xh,      // row-major [NN][128] fp16
                                             const int* __restrict__ nodes,
                                             const int* __restrict__ hedges,
                                             int* __restrict__ gchunk0, int* __restrict__ gchunk1,
                                             int* __restrict__ ghist, int* __restrict__ gstart,
                                             int E, int NCH, int nsort) {
    __shared__ FatSmem u;
    int t = threadIdx.x;

    if ((int)blockIdx.x < nsort) {
        // ---------------- chunksort ----------------
        int dir = blockIdx.x / NCH;
        int c   = blockIdx.x % NCH;
        const int* key = dir ? nodes  : hedges;
        const int* pay = dir ? hedges : nodes;
        int* gchunk    = dir ? gchunk1 : gchunk0;
        int e0 = c * CHSZ, e1 = min(E, e0 + CHSZ);

        for (int i = t; i < NBUK; i += 256) u.s.hist[i] = 0;
        __syncthreads();
        for (int e = e0 + t; e < e1; e += 256) atomicAdd(&u.s.hist[key[e] >> 6], 1);
        __syncthreads();

        int carry = 0;
        for (int base = 0; base < NBUK; base += 256) {
            int i = base + t;
            int v = (i < NBUK) ? u.s.hist[i] : 0;
            int tot;
            int ex = bscan256(v, u.s.s5, &tot);
            if (i < NBUK) u.s.cursor[i] = ex + carry;
            carry += tot;
        }
        __syncthreads();

        for (int b = t; b < NBUK; b += 256) {
            size_t idx = ((size_t)dir * NBUK + b) * NCH + c;
            ghist[idx]  = u.s.hist[b];
            gstart[idx] = u.s.cursor[b];
        }
        __syncthreads();

        for (int e = e0 + t; e < e1; e += 256) {
            int k = key[e];
            int pos = atomicAdd(&u.s.cursor[k >> 6], 1);
            u.s.pairs[pos] = ((k & 63) << 16) | pay[e];
        }
        __syncthreads();

        int n = e1 - e0;
        for (int i = t; i < n; i += 256) gchunk[(size_t)c * CHSZ + i] = u.s.pairs[i];
    } else {
        // ---------------- MFMA gemm: xh[64 rows] = X @ W -> fp16 ----------------
        int gb = blockIdx.x - nsort;
        int row0 = gb * 64;

        // stage X tile: f32 -> fp16, XOR-swizzled LDS (byte ^= (row&7)<<4)
        const float4* X4 = (const float4*)X;
        for (int i = t; i < 64 * 32; i += 256) {
            int r = i >> 5, cq = i & 31;           // row, float4-col
            int gr = row0 + r;
            float4 xv = (gr < NN) ? X4[(size_t)gr * 32 + cq]
                                  : make_float4(0.f, 0.f, 0.f, 0.f);
            PK4 pk;
            pk.h[0] = (f16)xv.x; pk.h[1] = (f16)xv.y;
            pk.h[2] = (f16)xv.z; pk.h[3] = (f16)xv.w;
            int byte = (r * 256 + cq * 8) ^ ((r & 7) << 4);
            *(uint2*)((char*)u.g.sXh + byte) = pk.u2;
        }
        __syncthreads();

        int l = t & 63, w = t >> 6;
        int lr = l & 15, lk = l >> 4;              // row/col-in-tile, k-group
        f32x4 acc[8];
#pragma unroll
        for (int c = 0; c < 8; ++c) acc[c] = (f32x4){0.f, 0.f, 0.f, 0.f};

#pragma unroll
        for (int ks = 0; ks < 4; ++ks) {
            int rloc = w * 16 + lr;
            int abyte = (rloc * 256 + ks * 64 + lk * 16) ^ ((rloc & 7) << 4);
            f16x8 afrag = *(const f16x8*)((const char*)u.g.sXh + abyte);
#pragma unroll
            for (int c = 0; c < 8; ++c) {
                f16x8 bfrag = *(const f16x8*)(Wt + (c * 16 + lr) * 128 + ks * 32 + lk * 8);
                acc[c] = __builtin_amdgcn_mfma_f32_16x16x32_f16(afrag, bfrag, acc[c], 0, 0, 0);
            }
        }

        // epilogue: C/D col=lane&15, row=(lane>>4)*4+reg
#pragma unroll
        for (int c = 0; c < 8; ++c) {
            int col = c * 16 + lr;
#pragma unroll
            for (int j = 0; j < 4; ++j) {
                int row = row0 + w * 16 + lk * 4 + j;
                if (row < NN) xh[(size_t)row * 128 + col] = (f16)acc[c][j];
            }
        }
    }
}

// ---------------- 2: bucket totals -> global bucket starts -----------------------
__global__ __launch_bounds__(1024) void bucketbase_k(const int* __restrict__ ghist,
                                                     int* __restrict__ bstart,
                                                     int* __restrict__ off0, int* __restrict__ off1,
                                                     int E, int NCH) {
    __shared__ int s16[17];
    int dir = blockIdx.x;
    int t = threadIdx.x, lane = t & 63, wid = t >> 6;
    int v = 0;
    if (t < NBUK) {
        const int* row = ghist + ((size_t)dir * NBUK + t) * NCH;
        int s = 0;
#pragma unroll 4
        for (int c = 0; c < NCH; ++c) s += row[c];
        v = s;
    }
    int incl = wscan64(v, lane);
    if (lane == 63) s16[wid] = incl;
    __syncthreads();
    if (t < 16) {
        int x = s16[t], y = x;
#pragma unroll
        for (int s = 1; s < 16; s <<= 1) {
            int u = __shfl_up(y, s, 64);
            if (t >= s) y += u;
        }
        s16[t] = y - x;
    }
    __syncthreads();
    int ex = incl - v + s16[wid];
    if (t < NBUK) bstart[dir * NBUK + t] = ex;
    if (t == 0) (dir ? off1 : off0)[50000] = E;
}

// ---------------- 3: per-bucket merge + fine sort + scatter ----------------------
__global__ __launch_bounds__(256) void merge_scatter_k(const int* __restrict__ gchunk0, const int* __restrict__ gchunk1,
                                                       const int* __restrict__ ghist, const int* __restrict__ gstart,
                                                       const int* __restrict__ bstart,
                                                       ushort_t* __restrict__ adj0, ushort_t* __restrict__ adj1,
                                                       int* __restrict__ off0, int* __restrict__ off1,
                                                       int NCH) {
    __shared__ int ssrc[256];
    __shared__ int sdst[257];
    __shared__ int s5[5];
    __shared__ int pairsS[CHSZ];
    __shared__ int fcnt[64], foff[64], fcur[64];

    int dir = blockIdx.x / NBUK;
    int b   = blockIdx.x % NBUK;
    int t   = threadIdx.x;
    const int* gchunk   = dir ? gchunk1 : gchunk0;
    ushort_t* adj       = dir ? adj1 : adj0;
    int* offD           = dir ? off1 : off0;

    int len = 0, src = 0;
    if (t < NCH) {
        size_t idx = ((size_t)dir * NBUK + b) * NCH + t;
        len = ghist[idx];
        src = gstart[idx];
    }
    ssrc[t] = src;
    int tot;
    int ex = bscan256(len, s5, &tot);
    sdst[t] = ex;
    if (t == 0) sdst[256] = 0x7FFFFFFF;
    if (t < 64) fcnt[t] = 0;
    __syncthreads();
    int T = tot;

    int per = (T + 255) >> 8;
    int i0 = t * per, i1 = min(T, i0 + per);
    if (i0 < i1) {
        int lo = 0, hi = 255;
        while (lo < hi) {
            int mid = (lo + hi + 1) >> 1;
            if (sdst[mid] <= i0) lo = mid; else hi = mid - 1;
        }
        int c = lo;
        for (int i = i0; i < i1; ++i) {
            while (c < 255 && sdst[c + 1] <= i) ++c;
            int p = gchunk[(size_t)c * CHSZ + ssrc[c] + (i - sdst[c])];
            pairsS[i] = p;
            atomicAdd(&fcnt[p >> 16], 1);
        }
    }
    __syncthreads();

    int bst = bstart[dir * NBUK + b];
    if (t < 64) {
        int x = fcnt[t];
        int y = wscan64(x, t);
        foff[t] = y - x;
        fcur[t] = y - x;
        int d = b * 64 + t;
        if (d < 50000) offD[d] = bst + foff[t];
    }
    __syncthreads();

    for (int i = t; i < T; i += 256) {
        int p = pairsS[i];
        int slot = atomicAdd(&fcur[p >> 16], 1);
        adj[(size_t)bst + slot] = (ushort_t)(p & 0xFFFF);
    }
}

// ---------------- pass A: m[h] = B_inv[h] * sum_{v in h} x[v] --------------------
__global__ __launch_bounds__(256) void agg_a_k(const float4* __restrict__ x4,
                                               const ushort_t* __restrict__ adj,
                                               const int* __restrict__ off,
                                               float4* __restrict__ m4) {
    int t = threadIdx.x;
    int seg = blockIdx.x * 4 + (t >> 6);
    int l = t & 63;
    int rg = l >> 4, cc = l & 15;
    int p0 = off[seg], p1 = off[seg + 1];
    float acc[8] = {};
    int i = p0;
    for (; i + 16 <= p1; i += 16) {
        int r0 = adj[i + rg], r1 = adj[i + 4 + rg], r2 = adj[i + 8 + rg], r3 = adj[i + 12 + rg];
        HF4 u0, u1, u2, u3;
        u0.f4 = x4[(size_t)r0 * 16 + cc];
        u1.f4 = x4[(size_t)r1 * 16 + cc];
        u2.f4 = x4[(size_t)r2 * 16 + cc];
        u3.f4 = x4[(size_t)r3 * 16 + cc];
#pragma unroll
        for (int k = 0; k < 4; ++k) {
            float2 f0 = __half22float2(u0.h2[k]);
            float2 f1 = __half22float2(u1.h2[k]);
            float2 f2 = __half22float2(u2.h2[k]);
            float2 f3 = __half22float2(u3.h2[k]);
            acc[2 * k]     += (f0.x + f1.x) + (f2.x + f3.x);
            acc[2 * k + 1] += (f0.y + f1.y) + (f2.y + f3.y);
        }
    }
    for (; i < p1; i += 4) {
        int r = i + rg;
        if (r < p1) {
            HF4 u;
            u.f4 = x4[(size_t)adj[r] * 16 + cc];
#pragma unroll
            for (int k = 0; k < 4; ++k) {
                float2 f = __half22float2(u.h2[k]);
                acc[2 * k] += f.x; acc[2 * k + 1] += f.y;
            }
        }
    }
#pragma unroll
    for (int k = 0; k < 8; ++k) {
        acc[k] += __shfl_xor(acc[k], 16, 64);
        acc[k] += __shfl_xor(acc[k], 32, 64);
    }
    if (l < 16) {
        float inv = (p1 > p0) ? 1.0f / (float)(p1 - p0) : 0.0f;
        HF4 w;
#pragma unroll
        for (int k = 0; k < 4; ++k)
            w.h2[k] = __floats2half2_rn(acc[2 * k] * inv, acc[2 * k + 1] * inv);
        m4[(size_t)seg * 16 + cc] = w.f4;
    }
}

// ---------------- pass B: out[v] = softmax(D_inv[v]*sum m[h] + b) (fused) --------
__global__ __launch_bounds__(256) void agg_b_k(const float4* __restrict__ m4,
                                               const ushort_t* __restrict__ adj,
                                               const int* __restrict__ off,
                                               const float* __restrict__ bias,
                                               float4* __restrict__ out4) {
    int t = threadIdx.x;
    int seg = blockIdx.x * 4 + (t >> 6);
    int l = t & 63;
    int rg = l >> 4, cc = l & 15;
    int p0 = off[seg], p1 = off[seg + 1];
    float acc[8] = {};
    int i = p0;
    for (; i + 16 <= p1; i += 16) {
        int r0 = adj[i + rg], r1 = adj[i + 4 + rg], r2 = adj[i + 8 + rg], r3 = adj[i + 12 + rg];
        HF4 u0, u1, u2, u3;
        u0.f4 = m4[(size_t)r0 * 16 + cc];
        u1.f4 = m4[(size_t)r1 * 16 + cc];
        u2.f4 = m4[(size_t)r2 * 16 + cc];
        u3.f4 = m4[(size_t)r3 * 16 + cc];
#pragma unroll
        for (int k = 0; k < 4; ++k) {
            float2 f0 = __half22float2(u0.h2[k]);
            float2 f1 = __half22float2(u1.h2[k]);
            float2 f2 = __half22float2(u2.h2[k]);
            float2 f3 = __half22float2(u3.h2[k]);
            acc[2 * k]     += (f0.x + f1.x) + (f2.x + f3.x);
            acc[2 * k + 1] += (f0.y + f1.y) + (f2.y + f3.y);
        }
    }
    for (; i < p1; i += 4) {
        int r = i + rg;
        if (r < p1) {
            HF4 u;
            u.f4 = m4[(size_t)adj[r] * 16 + cc];
#pragma unroll
            for (int k = 0; k < 4; ++k) {
                float2 f = __half22float2(u.h2[k]);
                acc[2 * k] += f.x; acc[2 * k + 1] += f.y;
            }
        }
    }
#pragma unroll
    for (int k = 0; k < 8; ++k) {
        acc[k] += __shfl_xor(acc[k], 16, 64);
        acc[k] += __shfl_xor(acc[k], 32, 64);
    }
    float inv = (p1 > p0) ? 1.0f / (float)(p1 - p0) : 0.0f;
    const float4* b4 = (const float4*)bias;
    float4 bb0 = b4[cc * 2], bb1 = b4[cc * 2 + 1];
    float lg[8];
    lg[0] = acc[0] * inv + bb0.x; lg[1] = acc[1] * inv + bb0.y;
    lg[2] = acc[2] * inv + bb0.z; lg[3] = acc[3] * inv + bb0.w;
    lg[4] = acc[4] * inv + bb1.x; lg[5] = acc[5] * inv + bb1.y;
    lg[6] = acc[6] * inv + bb1.z; lg[7] = acc[7] * inv + bb1.w;

    float mx = lg[0];
#pragma unroll
    for (int k = 1; k < 8; ++k) mx = fmaxf(mx, lg[k]);
#pragma unroll
    for (int s = 1; s < 16; s <<= 1) mx = fmaxf(mx, __shfl_xor(mx, s, 16));
    float e[8], sm = 0.f;
#pragma unroll
    for (int k = 0; k < 8; ++k) { e[k] = __expf(lg[k] - mx); sm += e[k]; }
#pragma unroll
    for (int s = 1; s < 16; s <<= 1) sm += __shfl_xor(sm, s, 16);
    float r = 1.0f / sm;
    if (l < 16) {
        out4[(size_t)seg * 32 + cc * 2]     = make_float4(e[0] * r, e[1] * r, e[2] * r, e[3] * r);
        out4[(size_t)seg * 32 + cc * 2 + 1] = make_float4(e[4] * r, e[5] * r, e[6] * r, e[7] * r);
    }
}

// ---------------- launcher -------------------------------------------------------
extern "C" void kernel_launch(void* const* d_in, const int* in_sizes, int n_in,
                              void* d_out, int out_size, void* d_ws, size_t ws_size,
                              hipStream_t stream) {
    const float* X  = (const float*)d_in[0];
    const int*   ei = (const int*)d_in[1];
    const float* W  = (const float*)d_in[2];
    const float* b  = (const float*)d_in[3];

    int E = in_sizes[1] / 2;
    const int* nodes  = ei;
    const int* hedges = ei + E;
    int NCH = (E + CHSZ - 1) / CHSZ;       // 196 for E=1.6M (must be <= 256)
    int nsort = 2 * NCH;
    int gemmb = (NN + 63) / 64;            // 782 MFMA-gemm blocks

    // workspace layout (~50 MB)
    char* p = (char*)d_ws;
    f16* xh = (f16*)p;                    p += (size_t)NN * F * 2;            // 12.8MB
    f16* mh = (f16*)p;                    p += (size_t)NM * F * 2;            // 12.8MB
    ushort_t* adj0 = (ushort_t*)p;        p += (size_t)E * 2;                 // 3.2MB
    ushort_t* adj1 = (ushort_t*)p;        p += (size_t)E * 2;                 // 3.2MB
    int* ghist  = (int*)p;                p += (size_t)2 * NBUK * NCH * 4;    // 2.45MB
    int* gstart = (int*)p;                p += (size_t)2 * NBUK * NCH * 4;    // 2.45MB
    int* bstart = (int*)p;                p += (size_t)2 * NBUK * 4;
    int* off0   = (int*)p;                p += (size_t)(NN + 1) * 4;
    int* off1   = (int*)p;                p += (size_t)(NN + 1) * 4;
    f16* Wt     = (f16*)p;                p += (size_t)128 * 128 * 2;         // 32KB
    p = (char*)(((uintptr_t)p + 15) & ~(uintptr_t)15);
    int* gchunk0 = (int*)p;                                                   // NCH*CHSZ ints
    int* gchunk1 = gchunk0 + (size_t)NCH * CHSZ;

    wprep_k<<<64, 256, 0, stream>>>(W, Wt);
    fat_k<<<nsort + gemmb, 256, 0, stream>>>(X, Wt, xh, nodes, hedges,
                                             gchunk0, gchunk1, ghist, gstart, E, NCH, nsort);
    bucketbase_k<<<2, 1024, 0, stream>>>(ghist, bstart, off0, off1, E, NCH);
    merge_scatter_k<<<2 * NBUK, 256, 0, stream>>>(gchunk0, gchunk1, ghist, gstart, bstart,
                                                  adj0, adj1, off0, off1, NCH);
    agg_a_k<<<NM / 4, 256, 0, stream>>>((const float4*)xh, adj0, off0, (float4*)mh);
    agg_b_k<<<NN / 4, 256, 0, stream>>>((const float4*)mh, adj1, off1, b, (float4*)d_out);
}

// Round 11
// 182.211 us; speedup vs baseline: 3.0914x; 1.2601x over previous
//
#include <hip/hip_runtime.h>
#include <hip/hip_fp16.h>

#define NN 50000
#define NM 50000
#define F  128
#define NBUK 782      // ceil(50000/64) buckets of 64 dest ids
#define CHSZ 8192     // edges per sort chunk
typedef unsigned short ushort_t;
typedef _Float16 f16;
typedef f16 f16x8 __attribute__((ext_vector_type(8)));
typedef float f32x4 __attribute__((ext_vector_type(4)));

union HF4 { float4 f4; __half2 h2[4]; };
union PK4 { uint2 u2; f16 h[4]; };

// ---------------- block-scan helpers ---------------------------------------------
__device__ __forceinline__ int wscan64(int v, int lane) {
    int x = v;
#pragma unroll
    for (int s = 1; s < 64; s <<= 1) {
        int u = __shfl_up(x, s, 64);
        if (lane >= s) x += u;
    }
    return x;   // inclusive
}

__device__ __forceinline__ int bscan256(int v, int* s5, int* tot) {
    int t = threadIdx.x, lane = t & 63, wid = t >> 6;
    int incl = wscan64(v, lane);
    if (lane == 63) s5[wid] = incl;
    __syncthreads();
    if (t == 0) {
        int a = 0;
#pragma unroll
        for (int j = 0; j < 4; ++j) { int x = s5[j]; s5[j] = a; a += x; }
        s5[4] = a;
    }
    __syncthreads();
    int ex = incl - v + s5[wid];
    *tot = s5[4];
    __syncthreads();
    return ex;
}

// ---------------- W prep: Wt[col][k] fp16 (B-fragment-friendly, L2-hot) ----------
__global__ __launch_bounds__(256) void wprep_k(const float* __restrict__ W,
                                               f16* __restrict__ Wt) {
    int i = blockIdx.x * 256 + threadIdx.x;   // 16384
    int k = i >> 7, c = i & 127;
    Wt[c * 128 + k] = (f16)W[i];
}

// ---------------- fat kernel: chunksort blocks [0,nsort) + MFMA-gemm blocks ------
struct GemmSmem { f16 sXh[64 * 128]; };                                            // 16KB
struct SortSmem { int hist[NBUK]; int cursor[NBUK]; int pairs[CHSZ]; int s5[5]; }; // 39.4KB
union alignas(16) FatSmem { GemmSmem g; SortSmem s; };

__global__ __launch_bounds__(256) void fat_k(const float* __restrict__ X,
                                             const f16* __restrict__ Wt,
                                             f16* __restrict__ xh,      // row-major [NN][128] fp16
                                             const int* __restrict__ nodes,
                                             const int* __restrict__ hedges,
                                             int* __restrict__ gchunk0, int* __restrict__ gchunk1,
                                             int* __restrict__ ghist, int* __restrict__ gstart,
                                             int E, int NCH, int nsort) {
    __shared__ FatSmem u;
    int t = threadIdx.x;

    if ((int)blockIdx.x < nsort) {
        // ---------------- chunksort ----------------
        int dir = blockIdx.x / NCH;
        int c   = blockIdx.x % NCH;
        const int* key = dir ? nodes  : hedges;
        const int* pay = dir ? hedges : nodes;
        int* gchunk    = dir ? gchunk1 : gchunk0;
        int e0 = c * CHSZ, e1 = min(E, e0 + CHSZ);

        for (int i = t; i < NBUK; i += 256) u.s.hist[i] = 0;
        __syncthreads();
        for (int e = e0 + t; e < e1; e += 256) atomicAdd(&u.s.hist[key[e] >> 6], 1);
        __syncthreads();

        int carry = 0;
        for (int base = 0; base < NBUK; base += 256) {
            int i = base + t;
            int v = (i < NBUK) ? u.s.hist[i] : 0;
            int tot;
            int ex = bscan256(v, u.s.s5, &tot);
            if (i < NBUK) u.s.cursor[i] = ex + carry;
            carry += tot;
        }
        __syncthreads();

        for (int b = t; b < NBUK; b += 256) {
            size_t idx = ((size_t)dir * NBUK + b) * NCH + c;
            ghist[idx]  = u.s.hist[b];
            gstart[idx] = u.s.cursor[b];
        }
        __syncthreads();

        for (int e = e0 + t; e < e1; e += 256) {
            int k = key[e];
            int pos = atomicAdd(&u.s.cursor[k >> 6], 1);
            u.s.pairs[pos] = ((k & 63) << 16) | pay[e];
        }
        __syncthreads();

        int n = e1 - e0;
        for (int i = t; i < n; i += 256) gchunk[(size_t)c * CHSZ + i] = u.s.pairs[i];
    } else {
        // ---------------- MFMA gemm: xh[64 rows] = X @ W -> fp16 ----------------
        int gb = blockIdx.x - nsort;
        int row0 = gb * 64;

        // stage X tile: f32 -> fp16, XOR-swizzled LDS (byte ^= (row&7)<<4)
        const float4* X4 = (const float4*)X;
        for (int i = t; i < 64 * 32; i += 256) {
            int r = i >> 5, cq = i & 31;           // row, float4-col
            int gr = row0 + r;
            float4 xv = (gr < NN) ? X4[(size_t)gr * 32 + cq]
                                  : make_float4(0.f, 0.f, 0.f, 0.f);
            PK4 pk;
            pk.h[0] = (f16)xv.x; pk.h[1] = (f16)xv.y;
            pk.h[2] = (f16)xv.z; pk.h[3] = (f16)xv.w;
            int byte = (r * 256 + cq * 8) ^ ((r & 7) << 4);
            *(uint2*)((char*)u.g.sXh + byte) = pk.u2;
        }
        __syncthreads();

        int l = t & 63, w = t >> 6;
        int lr = l & 15, lk = l >> 4;              // row/col-in-tile, k-group
        f32x4 acc[8];
#pragma unroll
        for (int c = 0; c < 8; ++c) acc[c] = (f32x4){0.f, 0.f, 0.f, 0.f};

#pragma unroll
        for (int ks = 0; ks < 4; ++ks) {
            int rloc = w * 16 + lr;
            int abyte = (rloc * 256 + ks * 64 + lk * 16) ^ ((rloc & 7) << 4);
            f16x8 afrag = *(const f16x8*)((const char*)u.g.sXh + abyte);
#pragma unroll
            for (int c = 0; c < 8; ++c) {
                f16x8 bfrag = *(const f16x8*)(Wt + (c * 16 + lr) * 128 + ks * 32 + lk * 8);
                acc[c] = __builtin_amdgcn_mfma_f32_16x16x32_f16(afrag, bfrag, acc[c], 0, 0, 0);
            }
        }

        // epilogue: C/D col=lane&15, row=(lane>>4)*4+reg
#pragma unroll
        for (int c = 0; c < 8; ++c) {
            int col = c * 16 + lr;
#pragma unroll
            for (int j = 0; j < 4; ++j) {
                int row = row0 + w * 16 + lk * 4 + j;
                if (row < NN) xh[(size_t)row * 128 + col] = (f16)acc[c][j];
            }
        }
    }
}

// ---------------- 2a: per-row sum of ghist (1 wave per row) ----------------------
__global__ __launch_bounds__(256) void rowsum_k(const int* __restrict__ ghist,
                                                int* __restrict__ bsum, int NCH) {
    int row = blockIdx.x * 4 + (threadIdx.x >> 6);
    int l = threadIdx.x & 63;
    if (row >= 2 * NBUK) return;
    const int* r = ghist + (size_t)row * NCH;
    int s = 0;
    for (int c = l; c < NCH; c += 64) s += r[c];
#pragma unroll
    for (int k = 32; k >= 1; k >>= 1) s += __shfl_xor(s, k, 64);
    if (l == 0) bsum[row] = s;
}

// ---------------- 2b: scan bucket sums -> global bucket starts -------------------
__global__ __launch_bounds__(1024) void bucketbase_k(const int* __restrict__ bsum,
                                                     int* __restrict__ bstart,
                                                     int* __restrict__ off0, int* __restrict__ off1,
                                                     int E) {
    __shared__ int s16[17];
    int dir = blockIdx.x;
    int t = threadIdx.x, lane = t & 63, wid = t >> 6;
    int v = (t < NBUK) ? bsum[dir * NBUK + t] : 0;
    int incl = wscan64(v, lane);
    if (lane == 63) s16[wid] = incl;
    __syncthreads();
    if (t < 16) {
        int x = s16[t], y = x;
#pragma unroll
        for (int s = 1; s < 16; s <<= 1) {
            int u = __shfl_up(y, s, 64);
            if (t >= s) y += u;
        }
        s16[t] = y - x;
    }
    __syncthreads();
    int ex = incl - v + s16[wid];
    if (t < NBUK) bstart[dir * NBUK + t] = ex;
    if (t == 0) (dir ? off1 : off0)[50000] = E;
}

// ---------------- 3: per-bucket merge + fine sort + scatter ----------------------
__global__ __launch_bounds__(256) void merge_scatter_k(const int* __restrict__ gchunk0, const int* __restrict__ gchunk1,
                                                       const int* __restrict__ ghist, const int* __restrict__ gstart,
                                                       const int* __restrict__ bstart,
                                                       ushort_t* __restrict__ adj0, ushort_t* __restrict__ adj1,
                                                       int* __restrict__ off0, int* __restrict__ off1,
                                                       int NCH) {
    __shared__ int ssrc[256];
    __shared__ int sdst[257];
    __shared__ int s5[5];
    __shared__ int pairsS[CHSZ];
    __shared__ int fcnt[64], foff[64], fcur[64];

    int dir = blockIdx.x / NBUK;
    int b   = blockIdx.x % NBUK;
    int t   = threadIdx.x;
    const int* gchunk   = dir ? gchunk1 : gchunk0;
    ushort_t* adj       = dir ? adj1 : adj0;
    int* offD           = dir ? off1 : off0;

    int len = 0, src = 0;
    if (t < NCH) {
        size_t idx = ((size_t)dir * NBUK + b) * NCH + t;
        len = ghist[idx];
        src = gstart[idx];
    }
    ssrc[t] = src;
    int tot;
    int ex = bscan256(len, s5, &tot);
    sdst[t] = ex;
    if (t == 0) sdst[256] = 0x7FFFFFFF;
    if (t < 64) fcnt[t] = 0;
    __syncthreads();
    int T = tot;

    int per = (T + 255) >> 8;
    int i0 = t * per, i1 = min(T, i0 + per);
    if (i0 < i1) {
        int lo = 0, hi = 255;
        while (lo < hi) {
            int mid = (lo + hi + 1) >> 1;
            if (sdst[mid] <= i0) lo = mid; else hi = mid - 1;
        }
        int c = lo;
        for (int i = i0; i < i1; ++i) {
            while (c < 255 && sdst[c + 1] <= i) ++c;
            int p = gchunk[(size_t)c * CHSZ + ssrc[c] + (i - sdst[c])];
            pairsS[i] = p;
            atomicAdd(&fcnt[p >> 16], 1);
        }
    }
    __syncthreads();

    int bst = bstart[dir * NBUK + b];
    if (t < 64) {
        int x = fcnt[t];
        int y = wscan64(x, t);
        foff[t] = y - x;
        fcur[t] = y - x;
        int d = b * 64 + t;
        if (d < 50000) offD[d] = bst + foff[t];
    }
    __syncthreads();

    for (int i = t; i < T; i += 256) {
        int p = pairsS[i];
        int slot = atomicAdd(&fcur[p >> 16], 1);
        adj[(size_t)bst + slot] = (ushort_t)(p & 0xFFFF);
    }
}

// ---------------- pass A: m[h] = B_inv[h] * sum_{v in h} x[v] --------------------
__global__ __launch_bounds__(256) void agg_a_k(const float4* __restrict__ x4,
                                               const ushort_t* __restrict__ adj,
                                               const int* __restrict__ off,
                                               float4* __restrict__ m4) {
    int t = threadIdx.x;
    int seg = blockIdx.x * 4 + (t >> 6);
    int l = t & 63;
    int rg = l >> 4, cc = l & 15;
    int p0 = off[seg], p1 = off[seg + 1];
    float acc[8] = {};
    int i = p0;
    for (; i + 16 <= p1; i += 16) {
        int r0 = adj[i + rg], r1 = adj[i + 4 + rg], r2 = adj[i + 8 + rg], r3 = adj[i + 12 + rg];
        HF4 u0, u1, u2, u3;
        u0.f4 = x4[(size_t)r0 * 16 + cc];
        u1.f4 = x4[(size_t)r1 * 16 + cc];
        u2.f4 = x4[(size_t)r2 * 16 + cc];
        u3.f4 = x4[(size_t)r3 * 16 + cc];
#pragma unroll
        for (int k = 0; k < 4; ++k) {
            float2 f0 = __half22float2(u0.h2[k]);
            float2 f1 = __half22float2(u1.h2[k]);
            float2 f2 = __half22float2(u2.h2[k]);
            float2 f3 = __half22float2(u3.h2[k]);
            acc[2 * k]     += (f0.x + f1.x) + (f2.x + f3.x);
            acc[2 * k + 1] += (f0.y + f1.y) + (f2.y + f3.y);
        }
    }
    for (; i < p1; i += 4) {
        int r = i + rg;
        if (r < p1) {
            HF4 u;
            u.f4 = x4[(size_t)adj[r] * 16 + cc];
#pragma unroll
            for (int k = 0; k < 4; ++k) {
                float2 f = __half22float2(u.h2[k]);
                acc[2 * k] += f.x; acc[2 * k + 1] += f.y;
            }
        }
    }
#pragma unroll
    for (int k = 0; k < 8; ++k) {
        acc[k] += __shfl_xor(acc[k], 16, 64);
        acc[k] += __shfl_xor(acc[k], 32, 64);
    }
    if (l < 16) {
        float inv = (p1 > p0) ? 1.0f / (float)(p1 - p0) : 0.0f;
        HF4 w;
#pragma unroll
        for (int k = 0; k < 4; ++k)
            w.h2[k] = __floats2half2_rn(acc[2 * k] * inv, acc[2 * k + 1] * inv);
        m4[(size_t)seg * 16 + cc] = w.f4;
    }
}

// ---------------- pass B: out[v] = softmax(D_inv[v]*sum m[h] + b) (fused) --------
__global__ __launch_bounds__(256) void agg_b_k(const float4* __restrict__ m4,
                                               const ushort_t* __restrict__ adj,
                                               const int* __restrict__ off,
                                               const float* __restrict__ bias,
                                               float4* __restrict__ out4) {
    int t = threadIdx.x;
    int seg = blockIdx.x * 4 + (t >> 6);
    int l = t & 63;
    int rg = l >> 4, cc = l & 15;
    int p0 = off[seg], p1 = off[seg + 1];
    float acc[8] = {};
    int i = p0;
    for (; i + 16 <= p1; i += 16) {
        int r0 = adj[i + rg], r1 = adj[i + 4 + rg], r2 = adj[i + 8 + rg], r3 = adj[i + 12 + rg];
        HF4 u0, u1, u2, u3;
        u0.f4 = m4[(size_t)r0 * 16 + cc];
        u1.f4 = m4[(size_t)r1 * 16 + cc];
        u2.f4 = m4[(size_t)r2 * 16 + cc];
        u3.f4 = m4[(size_t)r3 * 16 + cc];
#pragma unroll
        for (int k = 0; k < 4; ++k) {
            float2 f0 = __half22float2(u0.h2[k]);
            float2 f1 = __half22float2(u1.h2[k]);
            float2 f2 = __half22float2(u2.h2[k]);
            float2 f3 = __half22float2(u3.h2[k]);
            acc[2 * k]     += (f0.x + f1.x) + (f2.x + f3.x);
            acc[2 * k + 1] += (f0.y + f1.y) + (f2.y + f3.y);
        }
    }
    for (; i < p1; i += 4) {
        int r = i + rg;
        if (r < p1) {
            HF4 u;
            u.f4 = m4[(size_t)adj[r] * 16 + cc];
#pragma unroll
            for (int k = 0; k < 4; ++k) {
                float2 f = __half22float2(u.h2[k]);
                acc[2 * k] += f.x; acc[2 * k + 1] += f.y;
            }
        }
    }
#pragma unroll
    for (int k = 0; k < 8; ++k) {
        acc[k] += __shfl_xor(acc[k], 16, 64);
        acc[k] += __shfl_xor(acc[k], 32, 64);
    }
    float inv = (p1 > p0) ? 1.0f / (float)(p1 - p0) : 0.0f;
    const float4* b4 = (const float4*)bias;
    float4 bb0 = b4[cc * 2], bb1 = b4[cc * 2 + 1];
    float lg[8];
    lg[0] = acc[0] * inv + bb0.x; lg[1] = acc[1] * inv + bb0.y;
    lg[2] = acc[2] * inv + bb0.z; lg[3] = acc[3] * inv + bb0.w;
    lg[4] = acc[4] * inv + bb1.x; lg[5] = acc[5] * inv + bb1.y;
    lg[6] = acc[6] * inv + bb1.z; lg[7] = acc[7] * inv + bb1.w;

    float mx = lg[0];
#pragma unroll
    for (int k = 1; k < 8; ++k) mx = fmaxf(mx, lg[k]);
#pragma unroll
    for (int s = 1; s < 16; s <<= 1) mx = fmaxf(mx, __shfl_xor(mx, s, 16));
    float e[8], sm = 0.f;
#pragma unroll
    for (int k = 0; k < 8; ++k) { e[k] = __expf(lg[k] - mx); sm += e[k]; }
#pragma unroll
    for (int s = 1; s < 16; s <<= 1) sm += __shfl_xor(sm, s, 16);
    float r = 1.0f / sm;
    if (l < 16) {
        out4[(size_t)seg * 32 + cc * 2]     = make_float4(e[0] * r, e[1] * r, e[2] * r, e[3] * r);
        out4[(size_t)seg * 32 + cc * 2 + 1] = make_float4(e[4] * r, e[5] * r, e[6] * r, e[7] * r);
    }
}

// ---------------- launcher -------------------------------------------------------
extern "C" void kernel_launch(void* const* d_in, const int* in_sizes, int n_in,
                              void* d_out, int out_size, void* d_ws, size_t ws_size,
                              hipStream_t stream) {
    const float* X  = (const float*)d_in[0];
    const int*   ei = (const int*)d_in[1];
    const float* W  = (const float*)d_in[2];
    const float* b  = (const float*)d_in[3];

    int E = in_sizes[1] / 2;
    const int* nodes  = ei;
    const int* hedges = ei + E;
    int NCH = (E + CHSZ - 1) / CHSZ;       // 196 for E=1.6M (must be <= 256)
    int nsort = 2 * NCH;
    int gemmb = (NN + 63) / 64;            // 782 MFMA-gemm blocks

    // workspace layout (~50 MB)
    char* p = (char*)d_ws;
    f16* xh = (f16*)p;                    p += (size_t)NN * F * 2;            // 12.8MB
    f16* mh = (f16*)p;                    p += (size_t)NM * F * 2;            // 12.8MB
    ushort_t* adj0 = (ushort_t*)p;        p += (size_t)E * 2;                 // 3.2MB
    ushort_t* adj1 = (ushort_t*)p;        p += (size_t)E * 2;                 // 3.2MB
    int* ghist  = (int*)p;                p += (size_t)2 * NBUK * NCH * 4;    // 2.45MB
    int* gstart = (int*)p;                p += (size_t)2 * NBUK * NCH * 4;    // 2.45MB
    int* bstart = (int*)p;                p += (size_t)2 * NBUK * 4;
    int* bsum   = (int*)p;                p += (size_t)2 * NBUK * 4;
    int* off0   = (int*)p;                p += (size_t)(NN + 1) * 4;
    int* off1   = (int*)p;                p += (size_t)(NN + 1) * 4;
    f16* Wt     = (f16*)p;                p += (size_t)128 * 128 * 2;         // 32KB
    p = (char*)(((uintptr_t)p + 15) & ~(uintptr_t)15);
    int* gchunk0 = (int*)p;                                                   // NCH*CHSZ ints
    int* gchunk1 = gchunk0 + (size_t)NCH * CHSZ;

    wprep_k<<<64, 256, 0, stream>>>(W, Wt);
    fat_k<<<nsort + gemmb, 256, 0, stream>>>(X, Wt, xh, nodes, hedges,
                                             gchunk0, gchunk1, ghist, gstart, E, NCH, nsort);
    rowsum_k<<<(2 * NBUK + 3) / 4, 256, 0, stream>>>(ghist, bsum, NCH);
    bucketbase_k<<<2, 1024, 0, stream>>>(bsum, bstart, off0, off1, E);
    merge_scatter_k<<<2 * NBUK, 256, 0, stream>>>(gchunk0, gchunk1, ghist, gstart, bstart,
                                                  adj0, adj1, off0, off1, NCH);
    agg_a_k<<<NM / 4, 256, 0, stream>>>((const float4*)xh, adj0, off0, (float4*)mh);
    agg_b_k<<<NN / 4, 256, 0, stream>>>((const float4*)mh, adj1, off1, b, (float4*)d_out);
}